// Round 1
// baseline (1480.067 us; speedup 1.0000x reference)
//
#include <hip/hip_runtime.h>
#include <math.h>

#define D   128
#define DA  8
#define DE  64
#define DMH 192

// ---------------------------------------------------------------- rowptr ----
__global__ void build_rowptr(const int* __restrict__ row, int* __restrict__ rowptr,
                             int E, int N) {
    int e = blockIdx.x * 256 + threadIdx.x;
    if (e >= E) return;
    int cur  = row[e];
    int prev = (e == 0) ? -1 : row[e - 1];
    for (int r = prev + 1; r <= cur; ++r) rowptr[r] = e;
    if (e == E - 1) {
        for (int r = cur + 1; r <= N; ++r) rowptr[r] = E;
    }
}

// ------------------------------------------------- fused wres/wr/wc GEMM ----
// t0 = X @ wres.T + bres ; ar = X @ wr.T ; ac = X @ wc.T
template<int R>
__global__ __launch_bounds__(192) void fuse_pre(
    const float* __restrict__ X, const float* __restrict__ wres,
    const float* __restrict__ bres, const float* __restrict__ wr,
    const float* __restrict__ wc, float* __restrict__ t0,
    float* __restrict__ ar, float* __restrict__ ac, int N)
{
    __shared__ float a[R][D];
    const int t = threadIdx.x;
    const long i0 = (long)blockIdx.x * R;
    for (int idx = t; idx < R * D; idx += 192) {
        int  r = idx >> 7;
        long i = i0 + r;
        a[r][idx & (D - 1)] = (i < N) ? X[i * D + (idx & (D - 1))] : 0.f;
    }
    __syncthreads();

    const float* wptr = nullptr;
    if (t < 128)      wptr = wres + t * D;
    else if (t < 136) wptr = wr + (t - 128) * D;
    else if (t < 144) wptr = wc + (t - 136) * D;

    float acc[R];
#pragma unroll
    for (int r = 0; r < R; ++r) acc[r] = 0.f;
    if (wptr) {
        for (int k = 0; k < D; k += 4) {
            float4 w4 = *(const float4*)(wptr + k);
#pragma unroll
            for (int r = 0; r < R; ++r) {
                float4 z4 = *(const float4*)&a[r][k];
                acc[r] += z4.x * w4.x + z4.y * w4.y + z4.z * w4.z + z4.w * w4.w;
            }
        }
    }
    if (t < 128) {
        float bv = bres[t];
#pragma unroll
        for (int r = 0; r < R; ++r) {
            long i = i0 + r;
            if (i < N) t0[i * D + t] = acc[r] + bv;
        }
    } else if (t < 136) {
#pragma unroll
        for (int r = 0; r < R; ++r) {
            long i = i0 + r;
            if (i < N) ar[i * DA + (t - 128)] = acc[r];
        }
    } else if (t < 144) {
#pragma unroll
        for (int r = 0; r < R; ++r) {
            long i = i0 + r;
            if (i < N) ac[i * DA + (t - 136)] = acc[r];
        }
    }
}

// -------------------------------------------------------------- edge s ------
// s = leaky_relu(dot8(ar[row], ac[col]) / sqrt(8)); sbuf = exp(s)
__global__ void edge_score(const int* __restrict__ row, const int* __restrict__ col,
                           const float* __restrict__ ar, const float* __restrict__ ac,
                           float* __restrict__ sbuf, int E)
{
    int e = blockIdx.x * 256 + threadIdx.x;
    if (e >= E) return;
    int r = row[e], c = col[e];
    float4 a0 = *(const float4*)&ar[(long)r * DA];
    float4 a1 = *(const float4*)&ar[(long)r * DA + 4];
    float4 c0 = *(const float4*)&ac[(long)c * DA];
    float4 c1 = *(const float4*)&ac[(long)c * DA + 4];
    float s = a0.x * c0.x + a0.y * c0.y + a0.z * c0.z + a0.w * c0.w
            + a1.x * c1.x + a1.y * c1.y + a1.z * c1.z + a1.w * c1.w;
    s *= 0.35355339059327373f;           // 1/sqrt(8)
    s = (s >= 0.f) ? s : 0.2f * s;       // leaky relu
    sbuf[e] = expf(s);                   // global-max shift cancels in the row norm
}

// ----------------------------------------------------------- aggregate ------
// agg[n] = (sum_e exp(s_e) * X[col_e]) / (sum_e exp(s_e) + eps), segment of n
__global__ __launch_bounds__(128) void aggregate(
    const int* __restrict__ rowptr, const int* __restrict__ col,
    const float* __restrict__ sbuf, const float* __restrict__ X,
    float* __restrict__ agg)
{
    const int n = blockIdx.x;
    const int t = threadIdx.x;
    const int e0 = rowptr[n], e1 = rowptr[n + 1];
    float acc = 0.f, dsum = 0.f;
    for (int e = e0; e < e1; ++e) {
        float se = sbuf[e];
        int   c  = col[e];
        dsum += se;
        acc  += se * X[(long)c * D + t];
    }
    agg[(long)n * D + t] = acc * (1.f / (dsum + 1e-15f));
}

// ------------------------------------------------------- generic 128-GEMM ---
// out = act(A @ W.T + bias [+ addend])   (in-place A==out is safe: row-local)
template<int R, bool RELU, bool ADD>
__global__ __launch_bounds__(128) void gemm128(
    const float* __restrict__ A, const float* __restrict__ W,
    const float* __restrict__ bias, const float* __restrict__ addend,
    float* __restrict__ out, int N)
{
    __shared__ float a[R][D];
    const int t = threadIdx.x;
    const long i0 = (long)blockIdx.x * R;
#pragma unroll
    for (int r = 0; r < R; ++r) {
        long i = i0 + r;
        a[r][t] = (i < N) ? A[i * D + t] : 0.f;
    }
    __syncthreads();
    float acc[R];
#pragma unroll
    for (int r = 0; r < R; ++r) acc[r] = 0.f;
    for (int k = 0; k < D; k += 4) {
        float4 w4 = *(const float4*)&W[(long)t * D + k];
#pragma unroll
        for (int r = 0; r < R; ++r) {
            float4 z4 = *(const float4*)&a[r][k];
            acc[r] += z4.x * w4.x + z4.y * w4.y + z4.z * w4.z + z4.w * w4.w;
        }
    }
    float bv = bias[t];
#pragma unroll
    for (int r = 0; r < R; ++r) {
        long i = i0 + r;
        if (i < N) {
            float v = acc[r] + bv;
            if (ADD)  v += addend[i * D + t];
            if (RELU) v = fmaxf(v, 0.f);
            out[i * D + t] = v;
        }
    }
}

// --------------------------------------------------------------- MLP tail ---
// z = h[src]*h[dst] ++ emb[ebh];  2x (GEMM192 + LN + relu);  f0; f1; sigmoid
template<int R>
__global__ __launch_bounds__(192) void mlp_tail(
    const float* __restrict__ h,
    const int* __restrict__ src, const int* __restrict__ dst,
    const int* __restrict__ ebh, const float* __restrict__ emb,
    const float* __restrict__ w0, const float* __restrict__ b0,
    const float* __restrict__ w1, const float* __restrict__ b1,
    const float* __restrict__ g, const float* __restrict__ bln,
    const float* __restrict__ f0w, const float* __restrict__ f0b,
    const float* __restrict__ f1w, const float* __restrict__ f1b,
    float* __restrict__ out, int B)
{
    __shared__ float z[R][DMH];
    __shared__ float red[2][3][R];
    const int t = threadIdx.x;
    const int lane = t & 63, wv = t >> 6;
    const long i0 = (long)blockIdx.x * R;

    // ---- build z rows
    for (int r = 0; r < R; ++r) {
        long i = i0 + r;
        if (i < B) {
            if (t < 128) z[r][t] = h[(long)src[i] * D + t] * h[(long)dst[i] * D + t];
            else         z[r][t] = emb[(long)ebh[i] * DE + (t - 128)];
        } else {
            z[r][t] = 0.f;
        }
    }
    __syncthreads();

    float val[R];
    const float gv = g[t], blv = bln[t];
    for (int layer = 0; layer < 2; ++layer) {
        const float* W  = layer ? w1 : w0;
        const float  bb = layer ? b1[t] : b0[t];
#pragma unroll
        for (int r = 0; r < R; ++r) val[r] = 0.f;
        for (int k = 0; k < DMH; k += 4) {
            float4 w4 = *(const float4*)&W[(long)t * DMH + k];
#pragma unroll
            for (int r = 0; r < R; ++r) {
                float4 z4 = *(const float4*)&z[r][k];
                val[r] += z4.x * w4.x + z4.y * w4.y + z4.z * w4.z + z4.w * w4.w;
            }
        }
        // bias + LN reductions (sum, sumsq over 192 cols per row)
#pragma unroll
        for (int r = 0; r < R; ++r) {
            float v = val[r] + bb;
            val[r] = v;
            float s1 = v, s2 = v * v;
#pragma unroll
            for (int off = 32; off; off >>= 1) {
                s1 += __shfl_xor(s1, off);
                s2 += __shfl_xor(s2, off);
            }
            if (lane == 0) { red[0][wv][r] = s1; red[1][wv][r] = s2; }
        }
        __syncthreads();
#pragma unroll
        for (int r = 0; r < R; ++r) {
            float mu = (red[0][0][r] + red[0][1][r] + red[0][2][r]) * (1.f / 192.f);
            float ms = (red[1][0][r] + red[1][1][r] + red[1][2][r]) * (1.f / 192.f);
            float var = ms - mu * mu;
            float rs  = rsqrtf(var + 1e-5f);
            float y   = (val[r] - mu) * rs * gv + blv;
            val[r]    = fmaxf(y, 0.f);
        }
        __syncthreads();                 // everyone done reading z / red
#pragma unroll
        for (int r = 0; r < R; ++r) z[r][t] = val[r];
        __syncthreads();
    }

    // ---- f0 (192->64), f1 (64->1), sigmoid
    if (t < 64) {
        float o[R];
#pragma unroll
        for (int r = 0; r < R; ++r) o[r] = 0.f;
        for (int k = 0; k < DMH; k += 4) {
            float4 w4 = *(const float4*)&f0w[(long)t * DMH + k];
#pragma unroll
            for (int r = 0; r < R; ++r) {
                float4 z4 = *(const float4*)&z[r][k];
                o[r] += z4.x * w4.x + z4.y * w4.y + z4.z * w4.z + z4.w * w4.w;
            }
        }
        const float f0bv = f0b[t], f1wv = f1w[t];
#pragma unroll
        for (int r = 0; r < R; ++r) {
            float p = (o[r] + f0bv) * f1wv;
#pragma unroll
            for (int off = 32; off; off >>= 1) p += __shfl_xor(p, off);
            if (lane == 0) red[0][0][r] = p;
        }
    }
    __syncthreads();
    if (t < R) {
        long i = i0 + t;
        if (i < B) {
            float xv = red[0][0][t] + f1b[0];
            out[i] = 1.f / (1.f + expf(-xv));
        }
    }
}

// ------------------------------------------------------------------ launch --
extern "C" void kernel_launch(void* const* d_in, const int* in_sizes, int n_in,
                              void* d_out, int out_size, void* d_ws, size_t ws_size,
                              hipStream_t stream)
{
    const float* x      = (const float*)d_in[0];
    const int*   row    = (const int*)d_in[1];
    const int*   col    = (const int*)d_in[2];
    const int*   eb_src = (const int*)d_in[3];
    const int*   eb_dst = (const int*)d_in[4];
    const int*   eb_h   = (const int*)d_in[5];
    const float* l_wres[2] = {(const float*)d_in[6],  (const float*)d_in[14]};
    const float* l_bres[2] = {(const float*)d_in[7],  (const float*)d_in[15]};
    const float* l_wr[2]   = {(const float*)d_in[8],  (const float*)d_in[16]};
    const float* l_wc[2]   = {(const float*)d_in[9],  (const float*)d_in[17]};
    const float* l_wx[2]   = {(const float*)d_in[10], (const float*)d_in[18]};
    const float* l_bx[2]   = {(const float*)d_in[11], (const float*)d_in[19]};
    const float* l_wo[2]   = {(const float*)d_in[12], (const float*)d_in[20]};
    const float* l_bo[2]   = {(const float*)d_in[13], (const float*)d_in[21]};
    const float* emb_h  = (const float*)d_in[22];
    const float* mlp0_w = (const float*)d_in[23];
    const float* mlp0_b = (const float*)d_in[24];
    const float* mlp1_w = (const float*)d_in[25];
    const float* mlp1_b = (const float*)d_in[26];
    const float* ln_g   = (const float*)d_in[27];
    const float* ln_b   = (const float*)d_in[28];
    const float* f0_w   = (const float*)d_in[29];
    const float* f0_b   = (const float*)d_in[30];
    const float* f1_w   = (const float*)d_in[31];
    const float* f1_b   = (const float*)d_in[32];

    const int N = in_sizes[0] / D;
    const int E = in_sizes[1];
    const int B = in_sizes[3];

    // workspace layout (all f32 unless noted)
    float* tbuf   = (float*)d_ws;                  // [N,128]
    float* aggbuf = tbuf   + (size_t)N * D;        // [N,128]
    float* hbuf   = aggbuf + (size_t)N * D;        // [N,128]
    float* arb    = hbuf   + (size_t)N * D;        // [N,8]
    float* acb    = arb    + (size_t)N * DA;       // [N,8]
    float* sbuf   = acb    + (size_t)N * DA;       // [E]
    int*   rowptr = (int*)(sbuf + (size_t)E);      // [N+1]

    constexpr int R = 32;
    const int nbN = (N + R - 1) / R;
    const int nbE = (E + 255) / 256;
    const int nbB = (B + R - 1) / R;

    build_rowptr<<<nbE, 256, 0, stream>>>(row, rowptr, E, N);

    const float* lin[2] = {x, hbuf};
    float* lout[2] = {hbuf, tbuf};   // layer0 -> hbuf (relu'd), layer1 -> tbuf
    for (int L = 0; L < 2; ++L) {
        fuse_pre<R><<<nbN, 192, 0, stream>>>(lin[L], l_wres[L], l_bres[L],
                                             l_wr[L], l_wc[L], tbuf, arb, acb, N);
        edge_score<<<nbE, 256, 0, stream>>>(row, col, arb, acb, sbuf, E);
        aggregate<<<N, 128, 0, stream>>>(rowptr, col, sbuf, lin[L], aggbuf);
        gemm128<R, false, true><<<nbN, 128, 0, stream>>>(
            aggbuf, l_wx[L], l_bx[L], tbuf, aggbuf, N);          // y = t0 + agg@wx.T+bx
        if (L == 0)
            gemm128<R, true, false><<<nbN, 128, 0, stream>>>(
                aggbuf, l_wo[L], l_bo[L], nullptr, lout[L], N);  // relu
        else
            gemm128<R, false, false><<<nbN, 128, 0, stream>>>(
                aggbuf, l_wo[L], l_bo[L], nullptr, lout[L], N);  // no relu
    }

    mlp_tail<R><<<nbB, 192, 0, stream>>>(
        tbuf, eb_src, eb_dst, eb_h, emb_h,
        mlp0_w, mlp0_b, mlp1_w, mlp1_b, ln_g, ln_b,
        f0_w, f0_b, f1_w, f1_b, (float*)d_out, B);
}

// Round 2
// 620.795 us; speedup vs baseline: 2.3841x; 2.3841x over previous
//
#include <hip/hip_runtime.h>
#include <math.h>

#define D   128
#define DA  8
#define DE  64
#define DMH 192

typedef unsigned short u16;
typedef __attribute__((ext_vector_type(8))) short bfrag;   // 8 bf16 = 4 VGPRs
typedef __attribute__((ext_vector_type(4))) float facc;    // MFMA C/D

__device__ inline u16 f2bf(float v) {
    unsigned u = __float_as_uint(v);
    return (u16)((u + 0x7fffu + ((u >> 16) & 1u)) >> 16);   // RNE
}
__device__ inline bfrag pack8(const float* f) {
    bfrag r;
#pragma unroll
    for (int i = 0; i < 8; ++i) r[i] = (short)f2bf(f[i]);
    return r;
}

// ---- stage 64x128 f32 -> bf16 LDS, XOR-swizzled 16B chunks (256 threads) ----
__device__ inline void stage64x128(u16* lds, const float* src, long i0, int N) {
    const int t = threadIdx.x;
    const int row = t >> 2;
    const int col0 = (t & 3) * 32;
    const long i = i0 + row;
    __align__(16) float buf[32];
    if (i < N) {
        const float4* p = (const float4*)(src + i * (long)D + col0);
#pragma unroll
        for (int q = 0; q < 8; ++q) ((float4*)buf)[q] = p[q];
    } else {
#pragma unroll
        for (int q = 0; q < 32; ++q) buf[q] = 0.f;
    }
    char* base = (char*)lds + row * 256;
    const int sw = (row & 7) << 4;
#pragma unroll
    for (int c = 0; c < 4; ++c) {
        int chunk = (col0 >> 3) + c;
        *(bfrag*)(base + ((chunk * 16) ^ sw)) = pack8(buf + c * 8);
    }
}
__device__ inline bfrag afrag(const u16* lds, int row, int kb) {      // stride 256B
    int off = row * 256 + ((((kb >> 3) * 16)) ^ ((row & 7) << 4));
    return *(const bfrag*)((const char*)lds + off);
}
__device__ inline bfrag zfrag(const u16* lds, int row, int kb) {      // stride 384B
    int off = row * 384 + ((((kb >> 3) * 16)) ^ ((row & 7) << 4));
    return *(const bfrag*)((const char*)lds + off);
}

// ------------------------------------------------------------- weight prep --
struct PrepSrc { const float* p[13]; };
__global__ __launch_bounds__(256) void prep_weights(PrepSrc ps, u16* wb) {
    const int offs[14] = {0, 16384, 32768, 49152, 65536, 81920, 98304,
                          135168, 172032, 184320, 185344, 186368, 187392, 188416};
    int idx = blockIdx.x * 256 + threadIdx.x;
    if (idx >= 188416) return;
    int s = 0;
#pragma unroll
    for (int k = 1; k < 14; ++k) if (idx >= offs[k]) s = k;
    wb[idx] = f2bf(ps.p[s][idx - offs[s]]);
}

// ---------------------------------------------------------------- rowptr ----
__global__ void build_rowptr(const int* __restrict__ row, int* __restrict__ rowptr,
                             int E, int N) {
    int e = blockIdx.x * 256 + threadIdx.x;
    if (e >= E) return;
    int cur  = row[e];
    int prev = (e == 0) ? -1 : row[e - 1];
    for (int r = prev + 1; r <= cur; ++r) rowptr[r] = e;
    if (e == E - 1) {
        for (int r = cur + 1; r <= N; ++r) rowptr[r] = E;
    }
}

// ------------------------------------------------- fused wres/wr/wc MFMA ----
// t0 = X@wres.T + bres ; ar = X@wr.T ; ac = X@wc.T   (wrc = packed [wr;wc])
__global__ __launch_bounds__(256) void fuse_pre_mfma(
    const float* __restrict__ X, const u16* __restrict__ wres,
    const float* __restrict__ bres, const u16* __restrict__ wrc,
    float* __restrict__ t0, float* __restrict__ ar, float* __restrict__ ac, int N)
{
    __shared__ u16 alds[64 * 128];
    const long i0 = (long)blockIdx.x * 64;
    stage64x128(alds, X, i0, N);
    __syncthreads();
    const int w = threadIdx.x >> 6, l = threadIdx.x & 63;
    const int lg = l >> 4, l16 = l & 15;
    facc acc[9];
#pragma unroll
    for (int ct = 0; ct < 9; ++ct) acc[ct] = (facc){0, 0, 0, 0};
    for (int ks = 0; ks < 4; ++ks) {
        int kb = ks * 32 + lg * 8;
        bfrag a = afrag(alds, w * 16 + l16, kb);
#pragma unroll
        for (int ct = 0; ct < 9; ++ct) {
            const u16* wp = (ct < 8) ? (wres + (size_t)(ct * 16 + l16) * D + kb)
                                     : (wrc + (size_t)l16 * D + kb);
            bfrag b = *(const bfrag*)wp;
            acc[ct] = __builtin_amdgcn_mfma_f32_16x16x32_bf16(a, b, acc[ct], 0, 0, 0);
        }
    }
#pragma unroll
    for (int ct = 0; ct < 9; ++ct) {
#pragma unroll
        for (int j = 0; j < 4; ++j) {
            long i = i0 + w * 16 + lg * 4 + j;
            if (i >= N) continue;
            if (ct < 8) {
                int col = ct * 16 + l16;
                t0[i * (long)D + col] = acc[ct][j] + bres[col];
            } else {
                if (l16 < 8) ar[i * (long)DA + l16] = acc[ct][j];
                else         ac[i * (long)DA + (l16 - 8)] = acc[ct][j];
            }
        }
    }
}

// -------------------------------------------------------------- edge s ------
__global__ void edge_score(const int* __restrict__ row, const int* __restrict__ col,
                           const float* __restrict__ ar, const float* __restrict__ ac,
                           float* __restrict__ sbuf, int E)
{
    int e = blockIdx.x * 256 + threadIdx.x;
    if (e >= E) return;
    int r = row[e], c = col[e];
    float4 a0 = *(const float4*)&ar[(long)r * DA];
    float4 a1 = *(const float4*)&ar[(long)r * DA + 4];
    float4 c0 = *(const float4*)&ac[(long)c * DA];
    float4 c1 = *(const float4*)&ac[(long)c * DA + 4];
    float s = a0.x * c0.x + a0.y * c0.y + a0.z * c0.z + a0.w * c0.w
            + a1.x * c1.x + a1.y * c1.y + a1.z * c1.z + a1.w * c1.w;
    s *= 0.35355339059327373f;           // 1/sqrt(8)
    s = (s >= 0.f) ? s : 0.2f * s;       // leaky relu
    sbuf[e] = expf(s);                   // global-max shift cancels in the row norm
}

// ----------------------------------------------------------- aggregate ------
__global__ __launch_bounds__(128) void aggregate(
    const int* __restrict__ rowptr, const int* __restrict__ col,
    const float* __restrict__ sbuf, const float* __restrict__ X,
    float* __restrict__ agg)
{
    const int n = blockIdx.x;
    const int t = threadIdx.x;
    const int e0 = rowptr[n], e1 = rowptr[n + 1];
    float acc = 0.f, dsum = 0.f;
    for (int e = e0; e < e1; ++e) {
        float se = sbuf[e];
        int   c  = col[e];
        dsum += se;
        acc  += se * X[(long)c * D + t];
    }
    agg[(long)n * D + t] = acc * (1.f / (dsum + 1e-15f));
}

// ------------------------------------- fused wx(+t0) -> wo(+relu?) MFMA -----
template<bool RELU>
__global__ __launch_bounds__(256) void gtm_out_mfma(
    const float* __restrict__ agg, const float* __restrict__ t0,
    const u16* __restrict__ wx, const float* __restrict__ bx,
    const u16* __restrict__ wo, const float* __restrict__ bo,
    float* __restrict__ out, int N)
{
    __shared__ u16 lds[64 * 128];
    const long i0 = (long)blockIdx.x * 64;
    stage64x128(lds, agg, i0, N);
    __syncthreads();
    const int w = threadIdx.x >> 6, l = threadIdx.x & 63;
    const int lg = l >> 4, l16 = l & 15;
    facc acc[8];
#pragma unroll
    for (int ct = 0; ct < 8; ++ct) acc[ct] = (facc){0, 0, 0, 0};
    for (int ks = 0; ks < 4; ++ks) {
        int kb = ks * 32 + lg * 8;
        bfrag a = afrag(lds, w * 16 + l16, kb);
#pragma unroll
        for (int ct = 0; ct < 8; ++ct) {
            bfrag b = *(const bfrag*)(wx + (size_t)(ct * 16 + l16) * D + kb);
            acc[ct] = __builtin_amdgcn_mfma_f32_16x16x32_bf16(a, b, acc[ct], 0, 0, 0);
        }
    }
    __syncthreads();
    // y = acc + bx + t0 -> bf16 -> LDS (each wave owns its own 16-row band)
#pragma unroll
    for (int ct = 0; ct < 8; ++ct) {
        int col = ct * 16 + l16;
        float bxv = bx[col];
#pragma unroll
        for (int j = 0; j < 4; ++j) {
            int row = w * 16 + lg * 4 + j;
            long i = i0 + row;
            float tv = (i < N) ? t0[i * (long)D + col] : 0.f;
            float y = acc[ct][j] + bxv + tv;
            char* bp = (char*)lds + row * 256
                     + ((((col >> 3) * 16) ^ ((row & 7) << 4)) + (col & 7) * 2);
            *(u16*)bp = f2bf(y);
        }
    }
    __syncthreads();
#pragma unroll
    for (int ct = 0; ct < 8; ++ct) acc[ct] = (facc){0, 0, 0, 0};
    for (int ks = 0; ks < 4; ++ks) {
        int kb = ks * 32 + lg * 8;
        bfrag a = afrag(lds, w * 16 + l16, kb);
#pragma unroll
        for (int ct = 0; ct < 8; ++ct) {
            bfrag b = *(const bfrag*)(wo + (size_t)(ct * 16 + l16) * D + kb);
            acc[ct] = __builtin_amdgcn_mfma_f32_16x16x32_bf16(a, b, acc[ct], 0, 0, 0);
        }
    }
#pragma unroll
    for (int ct = 0; ct < 8; ++ct) {
        int col = ct * 16 + l16;
        float bov = bo[col];
#pragma unroll
        for (int j = 0; j < 4; ++j) {
            long i = i0 + w * 16 + lg * 4 + j;
            if (i < N) {
                float y = acc[ct][j] + bov;
                if (RELU) y = fmaxf(y, 0.f);
                out[i * (long)D + col] = y;
            }
        }
    }
}

// --------------------------------------------------------------- MLP tail ---
__global__ __launch_bounds__(256) void mlp_tail_mfma(
    const float* __restrict__ h,
    const int* __restrict__ src, const int* __restrict__ dst,
    const int* __restrict__ ebh, const float* __restrict__ emb,
    const u16* __restrict__ w0, const float* __restrict__ b0,
    const u16* __restrict__ w1, const float* __restrict__ b1,
    const float* __restrict__ g, const float* __restrict__ bln,
    const u16* __restrict__ f0w, const float* __restrict__ f0b,
    const float* __restrict__ f1w, const float* __restrict__ f1b,
    float* __restrict__ out, int B)
{
    __shared__ u16 z[64 * 192];                   // row stride 384B, 24 chunks
    const long i0 = (long)blockIdx.x * 64;
    const int t = threadIdx.x;
    // ---- build z = [h[src]*h[dst] ++ emb[ebh]] in bf16 (swizzled)
    for (int idx = t; idx < 64 * 24; idx += 256) {
        int row = idx / 24, chunk = idx % 24;
        long i = i0 + row;
        float v[8];
        if (i < B) {
            int col0 = chunk * 8;
            if (col0 < D) {
                const float* hs = h + (long)src[i] * D + col0;
                const float* hd = h + (long)dst[i] * D + col0;
                float4 a0 = *(const float4*)hs, a1 = *(const float4*)(hs + 4);
                float4 c0 = *(const float4*)hd, c1 = *(const float4*)(hd + 4);
                v[0] = a0.x * c0.x; v[1] = a0.y * c0.y; v[2] = a0.z * c0.z; v[3] = a0.w * c0.w;
                v[4] = a1.x * c1.x; v[5] = a1.y * c1.y; v[6] = a1.z * c1.z; v[7] = a1.w * c1.w;
            } else {
                const float* ep = emb + (long)ebh[i] * DE + (col0 - D);
                float4 e0 = *(const float4*)ep, e1 = *(const float4*)(ep + 4);
                v[0] = e0.x; v[1] = e0.y; v[2] = e0.z; v[3] = e0.w;
                v[4] = e1.x; v[5] = e1.y; v[6] = e1.z; v[7] = e1.w;
            }
        } else {
#pragma unroll
            for (int q = 0; q < 8; ++q) v[q] = 0.f;
        }
        char* bp = (char*)z + row * 384 + ((chunk * 16) ^ ((row & 7) << 4));
        *(bfrag*)bp = pack8(v);
    }
    __syncthreads();
    const int w = t >> 6, l = t & 63, lg = l >> 4, l16 = l & 15;
    facc acc[12];
    // ---- two (GEMM192 + LN + relu) layers; wave w owns row band w
    for (int layer = 0; layer < 2; ++layer) {
        const u16* Wp = layer ? w1 : w0;
        const float* bb = layer ? b1 : b0;
#pragma unroll
        for (int ct = 0; ct < 12; ++ct) acc[ct] = (facc){0, 0, 0, 0};
        for (int ks = 0; ks < 6; ++ks) {
            int kb = ks * 32 + lg * 8;
            bfrag a = zfrag(z, w * 16 + l16, kb);
#pragma unroll
            for (int ct = 0; ct < 12; ++ct) {
                bfrag b = *(const bfrag*)(Wp + (size_t)(ct * 16 + l16) * DMH + kb);
                acc[ct] = __builtin_amdgcn_mfma_f32_16x16x32_bf16(a, b, acc[ct], 0, 0, 0);
            }
        }
        float s1[4] = {0, 0, 0, 0}, s2[4] = {0, 0, 0, 0};
#pragma unroll
        for (int ct = 0; ct < 12; ++ct) {
            float bbv = bb[ct * 16 + l16];
#pragma unroll
            for (int j = 0; j < 4; ++j) {
                float xv = acc[ct][j] + bbv;
                acc[ct][j] = xv;
                s1[j] += xv; s2[j] += xv * xv;
            }
        }
#pragma unroll
        for (int j = 0; j < 4; ++j) {
#pragma unroll
            for (int off = 1; off < 16; off <<= 1) {
                s1[j] += __shfl_xor(s1[j], off);
                s2[j] += __shfl_xor(s2[j], off);
            }
        }
#pragma unroll
        for (int ct = 0; ct < 12; ++ct) {
            int col = ct * 16 + l16;
            float gv = g[col], bv = bln[col];
#pragma unroll
            for (int j = 0; j < 4; ++j) {
                float mu  = s1[j] * (1.f / 192.f);
                float var = s2[j] * (1.f / 192.f) - mu * mu;
                float y = (acc[ct][j] - mu) * rsqrtf(var + 1e-5f) * gv + bv;
                y = fmaxf(y, 0.f);
                int row = w * 16 + lg * 4 + j;
                char* bp = (char*)z + row * 384
                         + ((((col >> 3) * 16) ^ ((row & 7) << 4)) + (col & 7) * 2);
                *(u16*)bp = f2bf(y);
            }
        }
        __syncthreads();
    }
    // ---- f0 (192->64), f1 (64->1), sigmoid
    facc o[4];
#pragma unroll
    for (int ct = 0; ct < 4; ++ct) o[ct] = (facc){0, 0, 0, 0};
    for (int ks = 0; ks < 6; ++ks) {
        int kb = ks * 32 + lg * 8;
        bfrag a = zfrag(z, w * 16 + l16, kb);
#pragma unroll
        for (int ct = 0; ct < 4; ++ct) {
            bfrag b = *(const bfrag*)(f0w + (size_t)(ct * 16 + l16) * DMH + kb);
            o[ct] = __builtin_amdgcn_mfma_f32_16x16x32_bf16(a, b, o[ct], 0, 0, 0);
        }
    }
    float p[4] = {0, 0, 0, 0};
#pragma unroll
    for (int ct = 0; ct < 4; ++ct) {
        int col = ct * 16 + l16;
        float fb = f0b[col], fw = f1w[col];
#pragma unroll
        for (int j = 0; j < 4; ++j) p[j] += (o[ct][j] + fb) * fw;
    }
#pragma unroll
    for (int j = 0; j < 4; ++j) {
#pragma unroll
        for (int off = 1; off < 16; off <<= 1) p[j] += __shfl_xor(p[j], off);
    }
    if (l16 == 0) {
#pragma unroll
        for (int j = 0; j < 4; ++j) {
            long i = i0 + w * 16 + lg * 4 + j;
            if (i < B) out[i] = 1.f / (1.f + expf(-(p[j] + f1b[0])));
        }
    }
}

// ------------------------------------------------------------------ launch --
extern "C" void kernel_launch(void* const* d_in, const int* in_sizes, int n_in,
                              void* d_out, int out_size, void* d_ws, size_t ws_size,
                              hipStream_t stream)
{
    const float* x      = (const float*)d_in[0];
    const int*   row    = (const int*)d_in[1];
    const int*   col    = (const int*)d_in[2];
    const int*   eb_src = (const int*)d_in[3];
    const int*   eb_dst = (const int*)d_in[4];
    const int*   eb_h   = (const int*)d_in[5];
    const float* l_wres[2] = {(const float*)d_in[6],  (const float*)d_in[14]};
    const float* l_bres[2] = {(const float*)d_in[7],  (const float*)d_in[15]};
    const float* l_wr[2]   = {(const float*)d_in[8],  (const float*)d_in[16]};
    const float* l_wc[2]   = {(const float*)d_in[9],  (const float*)d_in[17]};
    const float* l_wx[2]   = {(const float*)d_in[10], (const float*)d_in[18]};
    const float* l_bx[2]   = {(const float*)d_in[11], (const float*)d_in[19]};
    const float* l_wo[2]   = {(const float*)d_in[12], (const float*)d_in[20]};
    const float* l_bo[2]   = {(const float*)d_in[13], (const float*)d_in[21]};
    const float* emb_h  = (const float*)d_in[22];
    const float* mlp0_w = (const float*)d_in[23];
    const float* mlp0_b = (const float*)d_in[24];
    const float* mlp1_w = (const float*)d_in[25];
    const float* mlp1_b = (const float*)d_in[26];
    const float* ln_g   = (const float*)d_in[27];
    const float* ln_b   = (const float*)d_in[28];
    const float* f0_w   = (const float*)d_in[29];
    const float* f0_b   = (const float*)d_in[30];
    const float* f1_w   = (const float*)d_in[31];
    const float* f1_b   = (const float*)d_in[32];

    const int N = in_sizes[0] / D;
    const int E = in_sizes[1];
    const int B = in_sizes[3];

    // workspace layout
    float* tbuf   = (float*)d_ws;                  // [N,128]  t0, later h_final
    float* aggbuf = tbuf   + (size_t)N * D;        // [N,128]
    float* hbuf   = aggbuf + (size_t)N * D;        // [N,128]
    float* arb    = hbuf   + (size_t)N * D;        // [N,8]
    float* acb    = arb    + (size_t)N * DA;       // [N,8]
    float* sbuf   = acb    + (size_t)N * DA;       // [E]
    int*   rowptr = (int*)(sbuf + (size_t)E);      // [N+1]
    uintptr_t wp  = (uintptr_t)(rowptr + (N + 1));
    wp = (wp + 15) & ~(uintptr_t)15;
    u16* WB = (u16*)wp;                            // 188416 bf16 weights

    const u16* WRES[2] = {WB + 0,     WB + 49152};
    const u16* WX[2]   = {WB + 16384, WB + 65536};
    const u16* WO[2]   = {WB + 32768, WB + 81920};
    const u16* MW0 = WB + 98304;
    const u16* MW1 = WB + 135168;
    const u16* F0W = WB + 172032;
    const u16* WRC[2] = {WB + 184320, WB + 186368};

    PrepSrc ps;
    ps.p[0] = l_wres[0]; ps.p[1] = l_wx[0]; ps.p[2] = l_wo[0];
    ps.p[3] = l_wres[1]; ps.p[4] = l_wx[1]; ps.p[5] = l_wo[1];
    ps.p[6] = mlp0_w;    ps.p[7] = mlp1_w;  ps.p[8] = f0_w;
    ps.p[9] = l_wr[0];   ps.p[10] = l_wc[0];
    ps.p[11] = l_wr[1];  ps.p[12] = l_wc[1];

    const int nb64 = (N + 63) / 64;
    const int nbE  = (E + 255) / 256;
    const int nbB  = (B + 63) / 64;

    prep_weights<<<(188416 + 255) / 256, 256, 0, stream>>>(ps, WB);
    build_rowptr<<<nbE, 256, 0, stream>>>(row, rowptr, E, N);

    const float* lin[2] = {x, hbuf};
    float* lout[2] = {hbuf, tbuf};
    for (int L = 0; L < 2; ++L) {
        fuse_pre_mfma<<<nb64, 256, 0, stream>>>(lin[L], WRES[L], l_bres[L],
                                                WRC[L], tbuf, arb, acb, N);
        edge_score<<<nbE, 256, 0, stream>>>(row, col, arb, acb, sbuf, E);
        aggregate<<<N, 128, 0, stream>>>(rowptr, col, sbuf, lin[L], aggbuf);
        if (L == 0)
            gtm_out_mfma<true><<<nb64, 256, 0, stream>>>(
                aggbuf, tbuf, WX[L], l_bx[L], WO[L], l_bo[L], lout[L], N);
        else
            gtm_out_mfma<false><<<nb64, 256, 0, stream>>>(
                aggbuf, tbuf, WX[L], l_bx[L], WO[L], l_bo[L], lout[L], N);
    }

    mlp_tail_mfma<<<nbB, 256, 0, stream>>>(
        tbuf, eb_src, eb_dst, eb_h, emb_h,
        MW0, mlp0_b, MW1, mlp1_b, ln_g, ln_b,
        F0W, f0_b, f1_w, f1_b, (float*)d_out, B);
}

// Round 3
// 501.705 us; speedup vs baseline: 2.9501x; 1.2374x over previous
//
#include <hip/hip_runtime.h>
#include <math.h>

#define D   128
#define DA  8
#define DE  64
#define DMH 192

typedef unsigned short u16;
typedef unsigned int   u32;
typedef __attribute__((ext_vector_type(8))) short bfrag;   // 8 bf16 = 4 VGPRs
typedef __attribute__((ext_vector_type(4))) float facc;    // MFMA C/D

__device__ inline u16 f2bf(float v) {
    unsigned u = __float_as_uint(v);
    return (u16)((u + 0x7fffu + ((u >> 16) & 1u)) >> 16);   // RNE
}
__device__ inline float bf2f(u16 v) { return __uint_as_float((u32)v << 16); }
__device__ inline bfrag pack8(const float* f) {
    bfrag r;
#pragma unroll
    for (int i = 0; i < 8; ++i) r[i] = (short)f2bf(f[i]);
    return r;
}
__device__ inline u32 pack2(float a, float b) {
    return (u32)f2bf(a) | ((u32)f2bf(b) << 16);
}

// ---- per-wave: copy 16 bf16 rows into swizzled LDS (stride 256B) ----------
__device__ inline void stage16(u16* wlds, const u16* __restrict__ src,
                               long r0, long nrows) {
    const int l = threadIdx.x & 63;
#pragma unroll
    for (int it = 0; it < 4; ++it) {
        int idx = it * 64 + l;             // 256 tasks: 16 rows x 16 chunks
        int row = idx >> 4, chunk = idx & 15;
        long i = r0 + row;
        bfrag v;
        if (i < nrows) v = *(const bfrag*)(src + i * D + chunk * 8);
        else {
#pragma unroll
            for (int k = 0; k < 8; ++k) v[k] = 0;
        }
        *(bfrag*)((char*)wlds + row * 256 + ((chunk * 16) ^ ((row & 7) << 4))) = v;
    }
}
__device__ inline bfrag afrag16(const u16* wlds, int row, int kb) {   // stride 256B
    int off = row * 256 + (((kb >> 3) * 16) ^ ((row & 7) << 4));
    return *(const bfrag*)((const char*)wlds + off);
}
__device__ inline bfrag zfrag16(const u16* wlds, int row, int kb) {   // stride 384B
    int off = row * 384 + (((kb >> 3) * 16) ^ ((row & 7) << 4));
    return *(const bfrag*)((const char*)wlds + off);
}

// ------------------------------------------------------------- weight prep --
struct PrepSrc { const float* p[13]; };
__global__ __launch_bounds__(256) void prep_weights(PrepSrc ps, u16* wb) {
    const int offs[14] = {0, 16384, 32768, 49152, 65536, 81920, 98304,
                          135168, 172032, 184320, 185344, 186368, 187392, 188416};
    int idx = blockIdx.x * 256 + threadIdx.x;
    if (idx >= 188416) return;
    int s = 0;
#pragma unroll
    for (int k = 1; k < 14; ++k) if (idx >= offs[k]) s = k;
    wb[idx] = f2bf(ps.p[s][idx - offs[s]]);
}

// --------------------------------------------------------- f32 -> bf16 copy -
__global__ __launch_bounds__(256) void convert_bf(const float* __restrict__ src,
                                                  u16* __restrict__ dst, long n8) {
    long i = (long)blockIdx.x * 256 + threadIdx.x;
    if (i >= n8) return;
    __align__(16) float buf[8];
    const float4* p = (const float4*)(src + i * 8);
    ((float4*)buf)[0] = p[0];
    ((float4*)buf)[1] = p[1];
    *(bfrag*)(dst + i * 8) = pack8(buf);
}

// ---------------------------------------------------------------- rowptr ----
__global__ void build_rowptr(const int* __restrict__ row, int* __restrict__ rowptr,
                             int E, int N) {
    int e = blockIdx.x * 256 + threadIdx.x;
    if (e >= E) return;
    int cur  = row[e];
    int prev = (e == 0) ? -1 : row[e - 1];
    for (int r = prev + 1; r <= cur; ++r) rowptr[r] = e;
    if (e == E - 1) {
        for (int r = cur + 1; r <= N; ++r) rowptr[r] = E;
    }
}

// ------------------------------------------------- fused wres/wr/wc MFMA ----
// t0 = X@wres.T + bres ; ar = X@wr.T ; ac = X@wc.T   (per-wave, no barriers)
__global__ __launch_bounds__(256) void fuse_pre_b(
    const u16* __restrict__ Xb, const u16* __restrict__ wres,
    const float* __restrict__ bres, const u16* __restrict__ wrc,
    float* __restrict__ t0, float* __restrict__ ar, float* __restrict__ ac, int N)
{
    __shared__ u16 alds[4][16 * D];
    const int w = threadIdx.x >> 6, l = threadIdx.x & 63;
    const int lg = l >> 4, l16 = l & 15;
    const long r0 = (long)blockIdx.x * 64 + w * 16;
    u16* wlds = alds[w];
    stage16(wlds, Xb, r0, N);
    asm volatile("s_waitcnt lgkmcnt(0)" ::: "memory");

    facc acc[9];
#pragma unroll
    for (int ct = 0; ct < 9; ++ct) acc[ct] = (facc){0, 0, 0, 0};
    for (int ks = 0; ks < 4; ++ks) {
        int kb = ks * 32 + lg * 8;
        bfrag a = afrag16(wlds, l16, kb);
#pragma unroll
        for (int ct = 0; ct < 9; ++ct) {
            const u16* wp = (ct < 8) ? (wres + (size_t)(ct * 16 + l16) * D + kb)
                                     : (wrc + (size_t)l16 * D + kb);
            bfrag b = *(const bfrag*)wp;
            acc[ct] = __builtin_amdgcn_mfma_f32_16x16x32_bf16(a, b, acc[ct], 0, 0, 0);
        }
    }
#pragma unroll
    for (int ct = 0; ct < 9; ++ct) {
#pragma unroll
        for (int j = 0; j < 4; ++j) {
            long i = r0 + lg * 4 + j;
            if (i >= N) continue;
            if (ct < 8) {
                int col = ct * 16 + l16;
                t0[i * (long)D + col] = acc[ct][j] + bres[col];
            } else {
                if (l16 < 8) ar[i * (long)DA + l16] = acc[ct][j];
                else         ac[i * (long)DA + (l16 - 8)] = acc[ct][j];
            }
        }
    }
}

// -------------------------------------------------------------- edge s ------
__global__ void edge_score(const int* __restrict__ row, const int* __restrict__ col,
                           const float* __restrict__ ar, const float* __restrict__ ac,
                           float* __restrict__ sbuf, int E)
{
    int e = blockIdx.x * 256 + threadIdx.x;
    if (e >= E) return;
    int r = row[e], c = col[e];
    float4 a0 = *(const float4*)&ar[(long)r * DA];
    float4 a1 = *(const float4*)&ar[(long)r * DA + 4];
    float4 c0 = *(const float4*)&ac[(long)c * DA];
    float4 c1 = *(const float4*)&ac[(long)c * DA + 4];
    float s = a0.x * c0.x + a0.y * c0.y + a0.z * c0.z + a0.w * c0.w
            + a1.x * c1.x + a1.y * c1.y + a1.z * c1.z + a1.w * c1.w;
    s *= 0.35355339059327373f;           // 1/sqrt(8)
    s = (s >= 0.f) ? s : 0.2f * s;       // leaky relu
    sbuf[e] = expf(s);                   // global-max shift cancels in the row norm
}

// ----------------------------------------------------------- aggregate ------
// one wave per node; 2 bf16 cols per lane (packed u32); bf16 out
__global__ __launch_bounds__(64) void aggregate_b(
    const int* __restrict__ rowptr, const int* __restrict__ col,
    const float* __restrict__ sbuf, const u32* __restrict__ Xb2,
    u32* __restrict__ aggb2, int N)
{
    const int n = blockIdx.x;
    if (n >= N) return;
    const int l = threadIdx.x;
    const int e0 = rowptr[n], e1 = rowptr[n + 1];
    float a0 = 0.f, a1 = 0.f, b0 = 0.f, b1 = 0.f, ds = 0.f;
    int e = e0;
    for (; e + 2 <= e1; e += 2) {
        int   c0 = col[e],  c1 = col[e + 1];
        float s0 = sbuf[e], s1 = sbuf[e + 1];
        u32 u0 = Xb2[(size_t)c0 * 64 + l];
        u32 u1 = Xb2[(size_t)c1 * 64 + l];
        ds += s0 + s1;
        a0 += s0 * __uint_as_float(u0 << 16);
        a1 += s0 * __uint_as_float(u0 & 0xffff0000u);
        b0 += s1 * __uint_as_float(u1 << 16);
        b1 += s1 * __uint_as_float(u1 & 0xffff0000u);
    }
    if (e < e1) {
        int   c0 = col[e];
        float s0 = sbuf[e];
        u32 u0 = Xb2[(size_t)c0 * 64 + l];
        ds += s0;
        a0 += s0 * __uint_as_float(u0 << 16);
        a1 += s0 * __uint_as_float(u0 & 0xffff0000u);
    }
    a0 += b0; a1 += b1;
    float sc = 1.f / (ds + 1e-15f);
    aggb2[(size_t)n * 64 + l] = pack2(a0 * sc, a1 * sc);
}

// ------------------------------------- fused wx(+t0) -> wo(+relu?) MFMA -----
template<bool RELU>
__global__ __launch_bounds__(256) void gtm_out_b(
    const u16* __restrict__ aggb, const float* __restrict__ t0,
    const u16* __restrict__ wx, const float* __restrict__ bx,
    const u16* __restrict__ wo, const float* __restrict__ bo,
    u16* __restrict__ hb, int N)
{
    __shared__ u16 alds[4][16 * D];
    const int w = threadIdx.x >> 6, l = threadIdx.x & 63;
    const int lg = l >> 4, l16 = l & 15;
    const long r0 = (long)blockIdx.x * 64 + w * 16;
    u16* wlds = alds[w];
    stage16(wlds, aggb, r0, N);
    asm volatile("s_waitcnt lgkmcnt(0)" ::: "memory");

    facc acc[8];
#pragma unroll
    for (int ct = 0; ct < 8; ++ct) acc[ct] = (facc){0, 0, 0, 0};
    for (int ks = 0; ks < 4; ++ks) {
        int kb = ks * 32 + lg * 8;
        bfrag a = afrag16(wlds, l16, kb);
#pragma unroll
        for (int ct = 0; ct < 8; ++ct) {
            bfrag b = *(const bfrag*)(wx + (size_t)(ct * 16 + l16) * D + kb);
            acc[ct] = __builtin_amdgcn_mfma_f32_16x16x32_bf16(a, b, acc[ct], 0, 0, 0);
        }
    }
    asm volatile("s_waitcnt lgkmcnt(0)" ::: "memory");   // drain reads before overwrite
    // y = acc + bx + t0 -> bf16 -> wave-local LDS
#pragma unroll
    for (int ct = 0; ct < 8; ++ct) {
        int col = ct * 16 + l16;
        float bxv = bx[col];
#pragma unroll
        for (int j = 0; j < 4; ++j) {
            int rl = lg * 4 + j;
            long i = r0 + rl;
            float tv = (i < N) ? t0[i * (long)D + col] : 0.f;
            float y = acc[ct][j] + bxv + tv;
            char* bp = (char*)wlds + rl * 256
                     + ((((col >> 3) * 16) ^ ((rl & 7) << 4)) + (col & 7) * 2);
            *(u16*)bp = f2bf(y);
        }
    }
    asm volatile("s_waitcnt lgkmcnt(0)" ::: "memory");   // writes land before reads
#pragma unroll
    for (int ct = 0; ct < 8; ++ct) acc[ct] = (facc){0, 0, 0, 0};
    for (int ks = 0; ks < 4; ++ks) {
        int kb = ks * 32 + lg * 8;
        bfrag a = afrag16(wlds, l16, kb);
#pragma unroll
        for (int ct = 0; ct < 8; ++ct) {
            bfrag b = *(const bfrag*)(wo + (size_t)(ct * 16 + l16) * D + kb);
            acc[ct] = __builtin_amdgcn_mfma_f32_16x16x32_bf16(a, b, acc[ct], 0, 0, 0);
        }
    }
#pragma unroll
    for (int ct = 0; ct < 8; ++ct) {
        int col = ct * 16 + l16;
        float bov = bo[col];
#pragma unroll
        for (int j = 0; j < 4; ++j) {
            long i = r0 + lg * 4 + j;
            if (i < N) {
                float y = acc[ct][j] + bov;
                if (RELU) y = fmaxf(y, 0.f);
                hb[i * (long)D + col] = f2bf(y);
            }
        }
    }
}

// --------------------------------------------------------------- MLP tail ---
__global__ __launch_bounds__(256) void mlp_tail_b(
    const u16* __restrict__ hb,
    const int* __restrict__ src, const int* __restrict__ dst,
    const int* __restrict__ ebh, const float* __restrict__ emb,
    const u16* __restrict__ w0, const float* __restrict__ b0,
    const u16* __restrict__ w1, const float* __restrict__ b1,
    const float* __restrict__ g, const float* __restrict__ bln,
    const u16* __restrict__ f0w, const float* __restrict__ f0b,
    const float* __restrict__ f1w, const float* __restrict__ f1b,
    float* __restrict__ out, int B)
{
    __shared__ u16 z[4][16 * DMH];                 // per-wave, row stride 384B
    const int w = threadIdx.x >> 6, l = threadIdx.x & 63;
    const int lg = l >> 4, l16 = l & 15;
    const long r0 = (long)blockIdx.x * 64 + w * 16;
    u16* wz = z[w];

    // ---- build z = [hb[src]*hb[dst] ++ emb[ebh]] (bf16, swizzled)
#pragma unroll
    for (int it = 0; it < 6; ++it) {
        int idx = it * 64 + l;                     // 384 tasks: 16 rows x 24 chunks
        int row = idx / 24, chunk = idx - row * 24;
        long i = r0 + row;
        __align__(16) float v[8];
        if (i < B) {
            if (chunk < 16) {
                bfrag hs = *(const bfrag*)(hb + (size_t)src[i] * D + chunk * 8);
                bfrag hd = *(const bfrag*)(hb + (size_t)dst[i] * D + chunk * 8);
#pragma unroll
                for (int k = 0; k < 8; ++k)
                    v[k] = bf2f((u16)hs[k]) * bf2f((u16)hd[k]);
            } else {
                const float* ep = emb + (size_t)ebh[i] * DE + (chunk - 16) * 8;
                float4 e0 = *(const float4*)ep, e1 = *(const float4*)(ep + 4);
                v[0] = e0.x; v[1] = e0.y; v[2] = e0.z; v[3] = e0.w;
                v[4] = e1.x; v[5] = e1.y; v[6] = e1.z; v[7] = e1.w;
            }
        } else {
#pragma unroll
            for (int k = 0; k < 8; ++k) v[k] = 0.f;
        }
        *(bfrag*)((char*)wz + row * 384 + ((chunk * 16) ^ ((row & 7) << 4))) = pack8(v);
    }
    asm volatile("s_waitcnt lgkmcnt(0)" ::: "memory");

    facc acc[12];
    for (int layer = 0; layer < 2; ++layer) {
        const u16* Wp = layer ? w1 : w0;
        const float* bb = layer ? b1 : b0;
#pragma unroll
        for (int ct = 0; ct < 12; ++ct) acc[ct] = (facc){0, 0, 0, 0};
        for (int ks = 0; ks < 6; ++ks) {
            int kb = ks * 32 + lg * 8;
            bfrag a = zfrag16(wz, l16, kb);
#pragma unroll
            for (int ct = 0; ct < 12; ++ct) {
                bfrag b = *(const bfrag*)(Wp + (size_t)(ct * 16 + l16) * DMH + kb);
                acc[ct] = __builtin_amdgcn_mfma_f32_16x16x32_bf16(a, b, acc[ct], 0, 0, 0);
            }
        }
        float s1[4] = {0, 0, 0, 0}, s2[4] = {0, 0, 0, 0};
#pragma unroll
        for (int ct = 0; ct < 12; ++ct) {
            float bbv = bb[ct * 16 + l16];
#pragma unroll
            for (int j = 0; j < 4; ++j) {
                float xv = acc[ct][j] + bbv;
                acc[ct][j] = xv;
                s1[j] += xv; s2[j] += xv * xv;
            }
        }
#pragma unroll
        for (int j = 0; j < 4; ++j) {
#pragma unroll
            for (int off = 1; off < 16; off <<= 1) {
                s1[j] += __shfl_xor(s1[j], off);
                s2[j] += __shfl_xor(s2[j], off);
            }
        }
        asm volatile("s_waitcnt lgkmcnt(0)" ::: "memory");  // reads done before overwrite
#pragma unroll
        for (int ct = 0; ct < 12; ++ct) {
            int col = ct * 16 + l16;
            float gv = g[col], bv = bln[col];
#pragma unroll
            for (int j = 0; j < 4; ++j) {
                float mu  = s1[j] * (1.f / 192.f);
                float var = s2[j] * (1.f / 192.f) - mu * mu;
                float y = (acc[ct][j] - mu) * rsqrtf(var + 1e-5f) * gv + bv;
                y = fmaxf(y, 0.f);
                int rl = lg * 4 + j;
                char* bp = (char*)wz + rl * 384
                         + ((((col >> 3) * 16) ^ ((rl & 7) << 4)) + (col & 7) * 2);
                *(u16*)bp = f2bf(y);
            }
        }
        asm volatile("s_waitcnt lgkmcnt(0)" ::: "memory");  // writes land before reads
    }

    // ---- f0 (192->64), f1 (64->1), sigmoid
    facc o[4];
#pragma unroll
    for (int ct = 0; ct < 4; ++ct) o[ct] = (facc){0, 0, 0, 0};
    for (int ks = 0; ks < 6; ++ks) {
        int kb = ks * 32 + lg * 8;
        bfrag a = zfrag16(wz, l16, kb);
#pragma unroll
        for (int ct = 0; ct < 4; ++ct) {
            bfrag b = *(const bfrag*)(f0w + (size_t)(ct * 16 + l16) * DMH + kb);
            o[ct] = __builtin_amdgcn_mfma_f32_16x16x32_bf16(a, b, o[ct], 0, 0, 0);
        }
    }
    float p[4] = {0, 0, 0, 0};
#pragma unroll
    for (int ct = 0; ct < 4; ++ct) {
        int col = ct * 16 + l16;
        float fb = f0b[col], fw = f1w[col];
#pragma unroll
        for (int j = 0; j < 4; ++j) p[j] += (o[ct][j] + fb) * fw;
    }
#pragma unroll
    for (int j = 0; j < 4; ++j) {
#pragma unroll
        for (int off = 1; off < 16; off <<= 1) p[j] += __shfl_xor(p[j], off);
    }
    if (l16 == 0) {
#pragma unroll
        for (int j = 0; j < 4; ++j) {
            long i = r0 + lg * 4 + j;
            if (i < B) out[i] = 1.f / (1.f + expf(-(p[j] + f1b[0])));
        }
    }
}

// ------------------------------------------------------------------ launch --
extern "C" void kernel_launch(void* const* d_in, const int* in_sizes, int n_in,
                              void* d_out, int out_size, void* d_ws, size_t ws_size,
                              hipStream_t stream)
{
    const float* x      = (const float*)d_in[0];
    const int*   row    = (const int*)d_in[1];
    const int*   col    = (const int*)d_in[2];
    const int*   eb_src = (const int*)d_in[3];
    const int*   eb_dst = (const int*)d_in[4];
    const int*   eb_h   = (const int*)d_in[5];
    const float* l_wres[2] = {(const float*)d_in[6],  (const float*)d_in[14]};
    const float* l_bres[2] = {(const float*)d_in[7],  (const float*)d_in[15]};
    const float* l_wr[2]   = {(const float*)d_in[8],  (const float*)d_in[16]};
    const float* l_wc[2]   = {(const float*)d_in[9],  (const float*)d_in[17]};
    const float* l_wx[2]   = {(const float*)d_in[10], (const float*)d_in[18]};
    const float* l_bx[2]   = {(const float*)d_in[11], (const float*)d_in[19]};
    const float* l_wo[2]   = {(const float*)d_in[12], (const float*)d_in[20]};
    const float* l_bo[2]   = {(const float*)d_in[13], (const float*)d_in[21]};
    const float* emb_h  = (const float*)d_in[22];
    const float* mlp0_w = (const float*)d_in[23];
    const float* mlp0_b = (const float*)d_in[24];
    const float* mlp1_w = (const float*)d_in[25];
    const float* mlp1_b = (const float*)d_in[26];
    const float* ln_g   = (const float*)d_in[27];
    const float* ln_b   = (const float*)d_in[28];
    const float* f0_w   = (const float*)d_in[29];
    const float* f0_b   = (const float*)d_in[30];
    const float* f1_w   = (const float*)d_in[31];
    const float* f1_b   = (const float*)d_in[32];

    const int N = in_sizes[0] / D;
    const int E = in_sizes[1];
    const int B = in_sizes[3];

    // workspace layout
    float* t0f  = (float*)d_ws;                       // [N,128] f32 residual
    float* arb  = t0f + (size_t)N * D;                // [N,8]
    float* acb  = arb + (size_t)N * DA;               // [N,8]
    float* sbuf = acb + (size_t)N * DA;               // [E]
    int* rowptr = (int*)(sbuf + (size_t)E);           // [N+1]
    uintptr_t bp = (uintptr_t)(rowptr + (N + 1));
    bp = (bp + 15) & ~(uintptr_t)15;
    u16* xb   = (u16*)bp;                             // [N,128] bf16
    u16* h0b  = xb  + (size_t)N * D;                  // [N,128] bf16
    u16* hfb  = h0b + (size_t)N * D;                  // [N,128] bf16
    u16* aggb = hfb + (size_t)N * D;                  // [N,128] bf16
    u16* WB   = aggb + (size_t)N * D;                 // 188416 bf16 weights

    const u16* WRES[2] = {WB + 0,     WB + 49152};
    const u16* WX[2]   = {WB + 16384, WB + 65536};
    const u16* WO[2]   = {WB + 32768, WB + 81920};
    const u16* MW0 = WB + 98304;
    const u16* MW1 = WB + 135168;
    const u16* F0W = WB + 172032;
    const u16* WRC[2] = {WB + 184320, WB + 186368};

    PrepSrc ps;
    ps.p[0] = l_wres[0]; ps.p[1] = l_wx[0]; ps.p[2] = l_wo[0];
    ps.p[3] = l_wres[1]; ps.p[4] = l_wx[1]; ps.p[5] = l_wo[1];
    ps.p[6] = mlp0_w;    ps.p[7] = mlp1_w;  ps.p[8] = f0_w;
    ps.p[9] = l_wr[0];   ps.p[10] = l_wc[0];
    ps.p[11] = l_wr[1];  ps.p[12] = l_wc[1];

    const int nb64 = (N + 63) / 64;
    const int nbE  = (E + 255) / 256;
    const int nbB  = (B + 63) / 64;
    const long n8  = (long)N * D / 8;

    prep_weights<<<(188416 + 255) / 256, 256, 0, stream>>>(ps, WB);
    build_rowptr<<<nbE, 256, 0, stream>>>(row, rowptr, E, N);
    convert_bf<<<(int)((n8 + 255) / 256), 256, 0, stream>>>(x, xb, n8);

    const u16* lin[2] = {xb, h0b};
    u16* lout[2] = {h0b, hfb};
    for (int L = 0; L < 2; ++L) {
        fuse_pre_b<<<nb64, 256, 0, stream>>>(lin[L], WRES[L], l_bres[L],
                                             WRC[L], t0f, arb, acb, N);
        edge_score<<<nbE, 256, 0, stream>>>(row, col, arb, acb, sbuf, E);
        aggregate_b<<<N, 64, 0, stream>>>(rowptr, col, sbuf,
                                          (const u32*)lin[L], (u32*)aggb, N);
        if (L == 0)
            gtm_out_b<true><<<nb64, 256, 0, stream>>>(
                aggb, t0f, WX[L], l_bx[L], WO[L], l_bo[L], lout[L], N);
        else
            gtm_out_b<false><<<nb64, 256, 0, stream>>>(
                aggb, t0f, WX[L], l_bx[L], WO[L], l_bo[L], lout[L], N);
    }

    mlp_tail_b<<<nbB, 256, 0, stream>>>(
        hfb, eb_src, eb_dst, eb_h, emb_h,
        MW0, mlp0_b, MW1, mlp1_b, ln_g, ln_b,
        F0W, f0_b, f1_w, f1_b, (float*)d_out, B);
}

// Round 4
// 484.290 us; speedup vs baseline: 3.0562x; 1.0360x over previous
//
#include <hip/hip_runtime.h>
#include <math.h>

#define D   128
#define DA  8
#define DE  64
#define DMH 192

typedef unsigned short u16;
typedef unsigned int   u32;
typedef __attribute__((ext_vector_type(8))) short bfrag;   // 8 bf16 = 4 VGPRs
typedef __attribute__((ext_vector_type(4))) float facc;    // MFMA C/D

__device__ inline u16 f2bf(float v) {
    unsigned u = __float_as_uint(v);
    return (u16)((u + 0x7fffu + ((u >> 16) & 1u)) >> 16);   // RNE
}
__device__ inline float bf2f(u16 v) { return __uint_as_float((u32)v << 16); }
__device__ inline u32 pack2(float a, float b) {
    return (u32)f2bf(a) | ((u32)f2bf(b) << 16);
}
__device__ inline bfrag bzero() {
    bfrag r;
#pragma unroll
    for (int i = 0; i < 8; ++i) r[i] = 0;
    return r;
}
// swizzled LDS fragment readers (row-XOR banks)
__device__ inline bfrag afrag16(const u16* wlds, int row, int kb) {   // stride 256B
    int off = row * 256 + (((kb >> 3) * 16) ^ ((row & 7) << 4));
    return *(const bfrag*)((const char*)wlds + off);
}
__device__ inline bfrag zfrag16(const u16* wlds, int row, int kb) {   // stride 384B
    int off = row * 384 + (((kb >> 3) * 16) ^ ((row & 7) << 4));
    return *(const bfrag*)((const char*)wlds + off);
}

// --------------------------------------------------------------- prep_all ---
// 1) weights -> bf16, repacked fragment-major: dst[((tct*nks+ks)*64+lane)*8+m]
//    = W[tct*16+(lane&15)][ks*32+(lane>>4)*8+m]  (emb stays row-major bf16)
// 2) x -> bf16   3) rowptr build
struct PrepSrc { const float* p[14]; };
__global__ __launch_bounds__(256) void prep_all(
    PrepSrc ps, u16* __restrict__ wb,
    const float* __restrict__ x, u16* __restrict__ xb, long n8,
    const int* __restrict__ row, int* __restrict__ rowptr, int E, int N)
{
    long task = (long)blockIdx.x * 256 + threadIdx.x;
    if (task < 194880) {
        int idx = (int)task;
        const int roff[13] = {0, 16384, 32768, 49152, 65536, 81920, 98304,
                              135168, 172032, 184320, 186368, 188416, 194880};
        int r = 0;
#pragma unroll
        for (int k = 1; k < 12; ++k) if (idx >= roff[k]) r = k;
        int local = idx - roff[r];
        float v;
        if (r == 11) {
            v = ps.p[13][local];                       // emb, plain
        } else {
            int K   = (r >= 6 && r <= 8) ? DMH : D;
            int nks = K >> 5;
            int m = local & 7, lane = (local >> 3) & 63;
            int l16 = lane & 15, lg = lane >> 4;
            int rest = local >> 9;
            int ks = rest % nks, tct = rest / nks;
            int rrow = tct * 16 + l16;
            int k = ks * 32 + lg * 8 + m;
            if (r == 9)       v = (rrow < 8) ? ps.p[9][rrow * D + k]
                                             : ps.p[10][(rrow - 8) * D + k];
            else if (r == 10) v = (rrow < 8) ? ps.p[11][rrow * D + k]
                                             : ps.p[12][(rrow - 8) * D + k];
            else              v = ps.p[r][(size_t)rrow * K + k];
        }
        wb[idx] = f2bf(v);
        return;
    }
    task -= 194880;
    if (task < n8) {                                    // x -> bf16
        long i = task;
        __align__(16) float buf[8];
        const float4* p = (const float4*)(x + i * 8);
        ((float4*)buf)[0] = p[0];
        ((float4*)buf)[1] = p[1];
        bfrag o;
#pragma unroll
        for (int k = 0; k < 8; ++k) o[k] = (short)f2bf(buf[k]);
        *(bfrag*)(xb + i * 8) = o;
        return;
    }
    task -= n8;
    if (task < E) {                                     // rowptr
        int e = (int)task;
        int cur  = row[e];
        int prev = (e == 0) ? -1 : row[e - 1];
        for (int r2 = prev + 1; r2 <= cur; ++r2) rowptr[r2] = e;
        if (e == E - 1)
            for (int r2 = cur + 1; r2 <= N; ++r2) rowptr[r2] = E;
    }
}

// --------------------------------------------------- ar/ac projection only --
__global__ __launch_bounds__(64, 4) void calc_arac(
    const u16* __restrict__ Xb, const u16* __restrict__ wrc,
    float* __restrict__ ar, float* __restrict__ ac, int N)
{
    const int l = threadIdx.x, l16 = l & 15, lg = l >> 4;
    const long r0 = (long)blockIdx.x * 16;
    const long ia = r0 + l16;
    bfrag a[4];
#pragma unroll
    for (int ks = 0; ks < 4; ++ks)
        a[ks] = (ia < N) ? *(const bfrag*)(Xb + ia * D + ks * 32 + lg * 8) : bzero();
    facc acc = (facc){0, 0, 0, 0};
#pragma unroll
    for (int ks = 0; ks < 4; ++ks) {
        bfrag b = *(const bfrag*)(wrc + ((ks * 64 + l) << 3));
        acc = __builtin_amdgcn_mfma_f32_16x16x32_bf16(a[ks], b, acc, 0, 0, 0);
    }
#pragma unroll
    for (int j = 0; j < 4; ++j) {
        long i = r0 + lg * 4 + j;
        if (i < N) {
            if (l16 < 8) ar[i * DA + l16] = acc[j];
            else         ac[i * DA + (l16 - 8)] = acc[j];
        }
    }
}

// -------------------------------------------------------------- edge s ------
__global__ void edge_score(const int* __restrict__ row, const int* __restrict__ col,
                           const float* __restrict__ ar, const float* __restrict__ ac,
                           float* __restrict__ sbuf, int E)
{
    int e = blockIdx.x * 256 + threadIdx.x;
    if (e >= E) return;
    int r = row[e], c = col[e];
    float4 a0 = *(const float4*)&ar[(long)r * DA];
    float4 a1 = *(const float4*)&ar[(long)r * DA + 4];
    float4 c0 = *(const float4*)&ac[(long)c * DA];
    float4 c1 = *(const float4*)&ac[(long)c * DA + 4];
    float s = a0.x * c0.x + a0.y * c0.y + a0.z * c0.z + a0.w * c0.w
            + a1.x * c1.x + a1.y * c1.y + a1.z * c1.z + a1.w * c1.w;
    s *= 0.35355339059327373f;           // 1/sqrt(8)
    s = (s >= 0.f) ? s : 0.2f * s;       // leaky relu
    sbuf[e] = expf(s);                   // global-max shift cancels in the row norm
}

// ----------------------------------------------------------- aggregate ------
// one wave per node; 2 bf16 cols/lane; 4 gathers in flight
__global__ __launch_bounds__(64) void aggregate_b(
    const int* __restrict__ rowptr, const int* __restrict__ col,
    const float* __restrict__ sbuf, const u32* __restrict__ Xb2,
    u32* __restrict__ aggb2, int N)
{
    const int n = blockIdx.x;
    if (n >= N) return;
    const int l = threadIdx.x;
    const int e0 = rowptr[n], e1 = rowptr[n + 1];
    float p0 = 0.f, p1 = 0.f, q0 = 0.f, q1 = 0.f, ds = 0.f;
    int e = e0;
    for (; e + 4 <= e1; e += 4) {
        int   c0 = col[e],     c1 = col[e + 1], c2 = col[e + 2], c3 = col[e + 3];
        float s0 = sbuf[e],    s1 = sbuf[e + 1];
        float s2 = sbuf[e + 2], s3 = sbuf[e + 3];
        u32 u0 = Xb2[(size_t)c0 * 64 + l];
        u32 u1 = Xb2[(size_t)c1 * 64 + l];
        u32 u2 = Xb2[(size_t)c2 * 64 + l];
        u32 u3 = Xb2[(size_t)c3 * 64 + l];
        ds += (s0 + s1) + (s2 + s3);
        p0 += s0 * __uint_as_float(u0 << 16);
        p1 += s0 * __uint_as_float(u0 & 0xffff0000u);
        q0 += s1 * __uint_as_float(u1 << 16);
        q1 += s1 * __uint_as_float(u1 & 0xffff0000u);
        p0 += s2 * __uint_as_float(u2 << 16);
        p1 += s2 * __uint_as_float(u2 & 0xffff0000u);
        q0 += s3 * __uint_as_float(u3 << 16);
        q1 += s3 * __uint_as_float(u3 & 0xffff0000u);
    }
    for (; e < e1; ++e) {
        int   c0 = col[e];
        float s0 = sbuf[e];
        u32 u0 = Xb2[(size_t)c0 * 64 + l];
        ds += s0;
        p0 += s0 * __uint_as_float(u0 << 16);
        p1 += s0 * __uint_as_float(u0 & 0xffff0000u);
    }
    p0 += q0; p1 += q1;
    float sc = 1.f / (ds + 1e-15f);
    aggb2[(size_t)n * 64 + l] = pack2(p0 * sc, p1 * sc);
}

// ---------------- fused (X@wres + agg@wx + biases) -> wo (+relu?) -----------
template<bool RELU>
__global__ __launch_bounds__(64, 3) void gtm_fused(
    const u16* __restrict__ Xb, const u16* __restrict__ aggb,
    const u16* __restrict__ wres, const float* __restrict__ bres,
    const u16* __restrict__ wx, const float* __restrict__ bx,
    const u16* __restrict__ wo, const float* __restrict__ bo,
    u16* __restrict__ hb, int N)
{
    __shared__ u16 ylds[16 * D];                       // 4KB, wave-private
    const int l = threadIdx.x, l16 = l & 15, lg = l >> 4;
    const long r0 = (long)blockIdx.x * 16;
    const long ia = r0 + l16;
    bfrag xa[4], ga[4];
#pragma unroll
    for (int ks = 0; ks < 4; ++ks) {
        if (ia < N) {
            xa[ks] = *(const bfrag*)(Xb   + ia * D + ks * 32 + lg * 8);
            ga[ks] = *(const bfrag*)(aggb + ia * D + ks * 32 + lg * 8);
        } else { xa[ks] = bzero(); ga[ks] = bzero(); }
    }
    facc acc[8];
#pragma unroll
    for (int ct = 0; ct < 8; ++ct) acc[ct] = (facc){0, 0, 0, 0};
#pragma unroll
    for (int ks = 0; ks < 4; ++ks) {
#pragma unroll
        for (int ct = 0; ct < 8; ++ct) {
            bfrag b1 = *(const bfrag*)(wres + (((ct * 4 + ks) * 64 + l) << 3));
            acc[ct] = __builtin_amdgcn_mfma_f32_16x16x32_bf16(xa[ks], b1, acc[ct], 0, 0, 0);
            bfrag b2 = *(const bfrag*)(wx + (((ct * 4 + ks) * 64 + l) << 3));
            acc[ct] = __builtin_amdgcn_mfma_f32_16x16x32_bf16(ga[ks], b2, acc[ct], 0, 0, 0);
        }
    }
    // y = acc + (bres+bx) -> bf16 -> swizzled LDS
#pragma unroll
    for (int ct = 0; ct < 8; ++ct) {
        int col = ct * 16 + l16;
        float bsum = bres[col] + bx[col];
#pragma unroll
        for (int j = 0; j < 4; ++j) {
            int rl = lg * 4 + j;
            *(u16*)((char*)ylds + rl * 256
                    + ((((col >> 3) * 16) ^ ((rl & 7) << 4)) + (col & 7) * 2))
                = f2bf(acc[ct][j] + bsum);
        }
    }
    asm volatile("s_waitcnt lgkmcnt(0)" ::: "memory");
    __builtin_amdgcn_sched_barrier(0);
#pragma unroll
    for (int ct = 0; ct < 8; ++ct) acc[ct] = (facc){0, 0, 0, 0};
#pragma unroll
    for (int ks = 0; ks < 4; ++ks) {
        bfrag a = afrag16(ylds, l16, ks * 32 + lg * 8);
#pragma unroll
        for (int ct = 0; ct < 8; ++ct) {
            bfrag b = *(const bfrag*)(wo + (((ct * 4 + ks) * 64 + l) << 3));
            acc[ct] = __builtin_amdgcn_mfma_f32_16x16x32_bf16(a, b, acc[ct], 0, 0, 0);
        }
    }
#pragma unroll
    for (int ct = 0; ct < 8; ++ct) {
        int col = ct * 16 + l16;
        float bov = bo[col];
#pragma unroll
        for (int j = 0; j < 4; ++j) {
            long i = r0 + lg * 4 + j;
            if (i < N) {
                float y = acc[ct][j] + bov;
                if (RELU) y = fmaxf(y, 0.f);
                hb[i * D + col] = f2bf(y);
            }
        }
    }
}

// --------------------------------------------------------------- MLP tail ---
__global__ __launch_bounds__(64, 3) void mlp_tail2(
    const u16* __restrict__ hb,
    const int* __restrict__ src, const int* __restrict__ dst,
    const int* __restrict__ ebh, const u16* __restrict__ embb,
    const u16* __restrict__ w0, const float* __restrict__ b0,
    const u16* __restrict__ w1, const float* __restrict__ b1,
    const float* __restrict__ g, const float* __restrict__ bln,
    const u16* __restrict__ f0w, const float* __restrict__ f0b,
    const float* __restrict__ f1w, const float* __restrict__ f1b,
    float* __restrict__ out, int B)
{
    __shared__ u16 wz[16 * DMH];                       // 6KB, wave-private
    const int l = threadIdx.x, l16 = l & 15, lg = l >> 4;
    const long r0 = (long)blockIdx.x * 16;
    const long ri = r0 + l16;
    // ---- z fragments built directly in registers
    bfrag za[6];
    if (ri < B) {
        int si = src[ri], di = dst[ri], hi2 = ebh[ri];
#pragma unroll
        for (int ks = 0; ks < 4; ++ks) {
            bfrag hs = *(const bfrag*)(hb + (size_t)si * D + ks * 32 + lg * 8);
            bfrag hd = *(const bfrag*)(hb + (size_t)di * D + ks * 32 + lg * 8);
            bfrag r;
#pragma unroll
            for (int k = 0; k < 8; ++k)
                r[k] = (short)f2bf(bf2f((u16)hs[k]) * bf2f((u16)hd[k]));
            za[ks] = r;
        }
        za[4] = *(const bfrag*)(embb + (size_t)hi2 * DE + lg * 8);
        za[5] = *(const bfrag*)(embb + (size_t)hi2 * DE + 32 + lg * 8);
    } else {
#pragma unroll
        for (int ks = 0; ks < 6; ++ks) za[ks] = bzero();
    }

    facc acc[12];
    for (int layer = 0; layer < 2; ++layer) {
        const u16* Wp = layer ? w1 : w0;
        const float* bb = layer ? b1 : b0;
#pragma unroll
        for (int ct = 0; ct < 12; ++ct) acc[ct] = (facc){0, 0, 0, 0};
        if (layer == 0) {
#pragma unroll
            for (int ks = 0; ks < 6; ++ks)
#pragma unroll
                for (int ct = 0; ct < 12; ++ct) {
                    bfrag b = *(const bfrag*)(Wp + (((ct * 6 + ks) * 64 + l) << 3));
                    acc[ct] = __builtin_amdgcn_mfma_f32_16x16x32_bf16(za[ks], b, acc[ct], 0, 0, 0);
                }
        } else {
#pragma unroll
            for (int ks = 0; ks < 6; ++ks) {
                bfrag a = zfrag16(wz, l16, ks * 32 + lg * 8);
#pragma unroll
                for (int ct = 0; ct < 12; ++ct) {
                    bfrag b = *(const bfrag*)(Wp + (((ct * 6 + ks) * 64 + l) << 3));
                    acc[ct] = __builtin_amdgcn_mfma_f32_16x16x32_bf16(a, b, acc[ct], 0, 0, 0);
                }
            }
        }
        // bias + LN (+relu) -> swizzled LDS
        float s1[4] = {0, 0, 0, 0}, s2[4] = {0, 0, 0, 0};
#pragma unroll
        for (int ct = 0; ct < 12; ++ct) {
            float bbv = bb[ct * 16 + l16];
#pragma unroll
            for (int j = 0; j < 4; ++j) {
                float xv = acc[ct][j] + bbv;
                acc[ct][j] = xv;
                s1[j] += xv; s2[j] += xv * xv;
            }
        }
#pragma unroll
        for (int j = 0; j < 4; ++j) {
#pragma unroll
            for (int off = 1; off < 16; off <<= 1) {
                s1[j] += __shfl_xor(s1[j], off);
                s2[j] += __shfl_xor(s2[j], off);
            }
        }
#pragma unroll
        for (int ct = 0; ct < 12; ++ct) {
            int cc = ct * 16 + l16;
            float gv = g[cc], bv = bln[cc];
#pragma unroll
            for (int j = 0; j < 4; ++j) {
                float mu  = s1[j] * (1.f / 192.f);
                float var = s2[j] * (1.f / 192.f) - mu * mu;
                float y = (acc[ct][j] - mu) * rsqrtf(var + 1e-5f) * gv + bv;
                y = fmaxf(y, 0.f);
                int rl = lg * 4 + j;
                *(u16*)((char*)wz + rl * 384
                        + ((((cc >> 3) * 16) ^ ((rl & 7) << 4)) + (cc & 7) * 2)) = f2bf(y);
            }
        }
        asm volatile("s_waitcnt lgkmcnt(0)" ::: "memory");
        __builtin_amdgcn_sched_barrier(0);
    }
    // ---- f0 (192->64), f1 (64->1), sigmoid
    facc o[4];
#pragma unroll
    for (int ct = 0; ct < 4; ++ct) o[ct] = (facc){0, 0, 0, 0};
#pragma unroll
    for (int ks = 0; ks < 6; ++ks) {
        bfrag a = zfrag16(wz, l16, ks * 32 + lg * 8);
#pragma unroll
        for (int ct = 0; ct < 4; ++ct) {
            bfrag b = *(const bfrag*)(f0w + (((ct * 6 + ks) * 64 + l) << 3));
            o[ct] = __builtin_amdgcn_mfma_f32_16x16x32_bf16(a, b, o[ct], 0, 0, 0);
        }
    }
    float p[4] = {0, 0, 0, 0};
#pragma unroll
    for (int ct = 0; ct < 4; ++ct) {
        int cc = ct * 16 + l16;
        float fb = f0b[cc], fw = f1w[cc];
#pragma unroll
        for (int j = 0; j < 4; ++j) p[j] += (o[ct][j] + fb) * fw;
    }
#pragma unroll
    for (int j = 0; j < 4; ++j) {
#pragma unroll
        for (int off = 1; off < 16; off <<= 1) p[j] += __shfl_xor(p[j], off);
    }
    if (l16 == 0) {
#pragma unroll
        for (int j = 0; j < 4; ++j) {
            long i = r0 + lg * 4 + j;
            if (i < B) out[i] = 1.f / (1.f + expf(-(p[j] + f1b[0])));
        }
    }
}

// ------------------------------------------------------------------ launch --
extern "C" void kernel_launch(void* const* d_in, const int* in_sizes, int n_in,
                              void* d_out, int out_size, void* d_ws, size_t ws_size,
                              hipStream_t stream)
{
    const float* x      = (const float*)d_in[0];
    const int*   row    = (const int*)d_in[1];
    const int*   col    = (const int*)d_in[2];
    const int*   eb_src = (const int*)d_in[3];
    const int*   eb_dst = (const int*)d_in[4];
    const int*   eb_h   = (const int*)d_in[5];
    const float* l_wres[2] = {(const float*)d_in[6],  (const float*)d_in[14]};
    const float* l_bres[2] = {(const float*)d_in[7],  (const float*)d_in[15]};
    const float* l_wr[2]   = {(const float*)d_in[8],  (const float*)d_in[16]};
    const float* l_wc[2]   = {(const float*)d_in[9],  (const float*)d_in[17]};
    const float* l_wx[2]   = {(const float*)d_in[10], (const float*)d_in[18]};
    const float* l_bx[2]   = {(const float*)d_in[11], (const float*)d_in[19]};
    const float* l_wo[2]   = {(const float*)d_in[12], (const float*)d_in[20]};
    const float* l_bo[2]   = {(const float*)d_in[13], (const float*)d_in[21]};
    const float* emb_h  = (const float*)d_in[22];
    const float* mlp0_w = (const float*)d_in[23];
    const float* mlp0_b = (const float*)d_in[24];
    const float* mlp1_w = (const float*)d_in[25];
    const float* mlp1_b = (const float*)d_in[26];
    const float* ln_g   = (const float*)d_in[27];
    const float* ln_b   = (const float*)d_in[28];
    const float* f0_w   = (const float*)d_in[29];
    const float* f0_b   = (const float*)d_in[30];
    const float* f1_w   = (const float*)d_in[31];
    const float* f1_b   = (const float*)d_in[32];

    const int N = in_sizes[0] / D;
    const int E = in_sizes[1];
    const int B = in_sizes[3];

    // workspace layout
    float* arb  = (float*)d_ws;                       // [N,8]
    float* acb  = arb + (size_t)N * DA;               // [N,8]
    float* sbuf = acb + (size_t)N * DA;               // [E]
    int* rowptr = (int*)(sbuf + (size_t)E);           // [N+1]
    uintptr_t bp = (uintptr_t)(rowptr + (N + 1));
    bp = (bp + 15) & ~(uintptr_t)15;
    u16* xb   = (u16*)bp;                             // [N,128] bf16
    u16* h0b  = xb  + (size_t)N * D;                  // [N,128] bf16
    u16* hfb  = h0b + (size_t)N * D;                  // [N,128] bf16
    u16* aggb = hfb + (size_t)N * D;                  // [N,128] bf16
    u16* WB   = aggb + (size_t)N * D;                 // 194880 bf16 weights

    const u16* WRES[2] = {WB + 0,     WB + 49152};
    const u16* WX[2]   = {WB + 16384, WB + 65536};
    const u16* WO[2]   = {WB + 32768, WB + 81920};
    const u16* MW0  = WB + 98304;
    const u16* MW1  = WB + 135168;
    const u16* F0W  = WB + 172032;
    const u16* WRC[2] = {WB + 184320, WB + 186368};
    const u16* EMBB = WB + 188416;

    PrepSrc ps;
    ps.p[0] = l_wres[0]; ps.p[1] = l_wx[0]; ps.p[2] = l_wo[0];
    ps.p[3] = l_wres[1]; ps.p[4] = l_wx[1]; ps.p[5] = l_wo[1];
    ps.p[6] = mlp0_w;    ps.p[7] = mlp1_w;  ps.p[8] = f0_w;
    ps.p[9] = l_wr[0];   ps.p[10] = l_wc[0];
    ps.p[11] = l_wr[1];  ps.p[12] = l_wc[1];
    ps.p[13] = emb_h;

    const int nb16  = (N + 15) / 16;
    const int nbE   = (E + 255) / 256;
    const int nbB16 = (B + 15) / 16;
    const long n8   = (long)N * D / 8;
    const long T    = 194880 + n8 + (long)E;
    const int nbT   = (int)((T + 255) / 256);

    prep_all<<<nbT, 256, 0, stream>>>(ps, WB, x, xb, n8, row, rowptr, E, N);

    const u16* lin[2] = {xb, h0b};
    u16* lout[2] = {h0b, hfb};
    for (int L = 0; L < 2; ++L) {
        calc_arac<<<nb16, 64, 0, stream>>>(lin[L], WRC[L], arb, acb, N);
        edge_score<<<nbE, 256, 0, stream>>>(row, col, arb, acb, sbuf, E);
        aggregate_b<<<N, 64, 0, stream>>>(rowptr, col, sbuf,
                                          (const u32*)lin[L], (u32*)aggb, N);
        if (L == 0)
            gtm_fused<true><<<nb16, 64, 0, stream>>>(
                lin[L], aggb, WRES[L], l_bres[L], WX[L], l_bx[L],
                WO[L], l_bo[L], lout[L], N);
        else
            gtm_fused<false><<<nb16, 64, 0, stream>>>(
                lin[L], aggb, WRES[L], l_bres[L], WX[L], l_bx[L],
                WO[L], l_bo[L], lout[L], N);
    }

    mlp_tail2<<<nbB16, 64, 0, stream>>>(
        hfb, eb_src, eb_dst, eb_h, EMBB,
        MW0, mlp0_b, MW1, mlp1_b, ln_g, ln_b,
        F0W, f0_b, f1_w, f1_b, (float*)d_out, B);
}

// Round 5
// 313.564 us; speedup vs baseline: 4.7201x; 1.5445x over previous
//
#include <hip/hip_runtime.h>
#include <math.h>

#define D   128
#define DA  8
#define DE  64
#define DMH 192

typedef unsigned short u16;
typedef unsigned int   u32;
typedef __attribute__((ext_vector_type(8))) short bfrag;   // 8 bf16 = 4 VGPRs
typedef __attribute__((ext_vector_type(4))) float facc;    // MFMA C/D

__device__ inline u16 f2bf(float v) {
    unsigned u = __float_as_uint(v);
    return (u16)((u + 0x7fffu + ((u >> 16) & 1u)) >> 16);   // RNE
}
__device__ inline float bf2f(u16 v) { return __uint_as_float((u32)v << 16); }
__device__ inline u32 pack2(float a, float b) {
    return (u32)f2bf(a) | ((u32)f2bf(b) << 16);
}
__device__ inline bfrag bzero() {
    bfrag r;
#pragma unroll
    for (int i = 0; i < 8; ++i) r[i] = 0;
    return r;
}
// swizzled LDS fragment readers (row-XOR banks)
__device__ inline bfrag afrag16(const u16* wlds, int row, int kb) {   // stride 256B
    int off = row * 256 + (((kb >> 3) * 16) ^ ((row & 7) << 4));
    return *(const bfrag*)((const char*)wlds + off);
}
__device__ inline bfrag zfrag16(const u16* wlds, int row, int kb) {   // stride 384B
    int off = row * 384 + (((kb >> 3) * 16) ^ ((row & 7) << 4));
    return *(const bfrag*)((const char*)wlds + off);
}

// --------------------------------------------------------------- prep_all ---
// 1) weights -> bf16, repacked fragment-major: dst[((tct*nks+ks)*64+lane)*8+m]
//    = W[tct*16+(lane&15)][ks*32+(lane>>4)*8+m]  (emb stays row-major bf16)
// 2) x -> bf16   3) rowptr build
struct PrepSrc { const float* p[14]; };
__global__ __launch_bounds__(256) void prep_all(
    PrepSrc ps, u16* __restrict__ wb,
    const float* __restrict__ x, u16* __restrict__ xb, long n8,
    const int* __restrict__ row, int* __restrict__ rowptr, int E, int N)
{
    long task = (long)blockIdx.x * 256 + threadIdx.x;
    if (task < 194880) {
        int idx = (int)task;
        const int roff[13] = {0, 16384, 32768, 49152, 65536, 81920, 98304,
                              135168, 172032, 184320, 186368, 188416, 194880};
        int r = 0;
#pragma unroll
        for (int k = 1; k < 12; ++k) if (idx >= roff[k]) r = k;
        int local = idx - roff[r];
        float v;
        if (r == 11) {
            v = ps.p[13][local];                       // emb, plain
        } else {
            int K   = (r >= 6 && r <= 8) ? DMH : D;
            int nks = K >> 5;
            int m = local & 7, lane = (local >> 3) & 63;
            int l16 = lane & 15, lg = lane >> 4;
            int rest = local >> 9;
            int ks = rest % nks, tct = rest / nks;
            int rrow = tct * 16 + l16;
            int k = ks * 32 + lg * 8 + m;
            if (r == 9)       v = (rrow < 8) ? ps.p[9][rrow * D + k]
                                             : ps.p[10][(rrow - 8) * D + k];
            else if (r == 10) v = (rrow < 8) ? ps.p[11][rrow * D + k]
                                             : ps.p[12][(rrow - 8) * D + k];
            else              v = ps.p[r][(size_t)rrow * K + k];
        }
        wb[idx] = f2bf(v);
        return;
    }
    task -= 194880;
    if (task < n8) {                                    // x -> bf16
        long i = task;
        __align__(16) float buf[8];
        const float4* p = (const float4*)(x + i * 8);
        ((float4*)buf)[0] = p[0];
        ((float4*)buf)[1] = p[1];
        bfrag o;
#pragma unroll
        for (int k = 0; k < 8; ++k) o[k] = (short)f2bf(buf[k]);
        *(bfrag*)(xb + i * 8) = o;
        return;
    }
    task -= n8;
    if (task < E) {                                     // rowptr
        int e = (int)task;
        int cur  = row[e];
        int prev = (e == 0) ? -1 : row[e - 1];
        for (int r2 = prev + 1; r2 <= cur; ++r2) rowptr[r2] = e;
        if (e == E - 1)
            for (int r2 = cur + 1; r2 <= N; ++r2) rowptr[r2] = E;
    }
}

// --------------------------------------------------- ar/ac projection only --
__global__ __launch_bounds__(64) void calc_arac(
    const u16* __restrict__ Xb, const u16* __restrict__ wrc,
    float* __restrict__ ar, float* __restrict__ ac, int N)
{
    const int l = threadIdx.x, l16 = l & 15, lg = l >> 4;
    const long r0 = (long)blockIdx.x * 16;
    const long ia = r0 + l16;
    bfrag a[4];
#pragma unroll
    for (int ks = 0; ks < 4; ++ks)
        a[ks] = (ia < N) ? *(const bfrag*)(Xb + ia * D + ks * 32 + lg * 8) : bzero();
    facc acc = (facc){0, 0, 0, 0};
#pragma unroll
    for (int ks = 0; ks < 4; ++ks) {
        bfrag b = *(const bfrag*)(wrc + ((ks * 64 + l) << 3));
        acc = __builtin_amdgcn_mfma_f32_16x16x32_bf16(a[ks], b, acc, 0, 0, 0);
    }
#pragma unroll
    for (int j = 0; j < 4; ++j) {
        long i = r0 + lg * 4 + j;
        if (i < N) {
            if (l16 < 8) ar[i * DA + l16] = acc[j];
            else         ac[i * DA + (l16 - 8)] = acc[j];
        }
    }
}

// -------------------------------------------------------------- edge s ------
__global__ void edge_score(const int* __restrict__ row, const int* __restrict__ col,
                           const float* __restrict__ ar, const float* __restrict__ ac,
                           float* __restrict__ sbuf, int E)
{
    int e = blockIdx.x * 256 + threadIdx.x;
    if (e >= E) return;
    int r = row[e], c = col[e];
    float4 a0 = *(const float4*)&ar[(long)r * DA];
    float4 a1 = *(const float4*)&ar[(long)r * DA + 4];
    float4 c0 = *(const float4*)&ac[(long)c * DA];
    float4 c1 = *(const float4*)&ac[(long)c * DA + 4];
    float s = a0.x * c0.x + a0.y * c0.y + a0.z * c0.z + a0.w * c0.w
            + a1.x * c1.x + a1.y * c1.y + a1.z * c1.z + a1.w * c1.w;
    s *= 0.35355339059327373f;           // 1/sqrt(8)
    s = (s >= 0.f) ? s : 0.2f * s;       // leaky relu
    sbuf[e] = expf(s);                   // global-max shift cancels in the row norm
}

// ----------------------------------------------------------- aggregate ------
// one wave per node; 2 bf16 cols/lane; 4 gathers in flight
__global__ __launch_bounds__(64) void aggregate_b(
    const int* __restrict__ rowptr, const int* __restrict__ col,
    const float* __restrict__ sbuf, const u32* __restrict__ Xb2,
    u32* __restrict__ aggb2, int N)
{
    const int n = blockIdx.x;
    if (n >= N) return;
    const int l = threadIdx.x;
    const int e0 = rowptr[n], e1 = rowptr[n + 1];
    float p0 = 0.f, p1 = 0.f, q0 = 0.f, q1 = 0.f, ds = 0.f;
    int e = e0;
    for (; e + 4 <= e1; e += 4) {
        int   c0 = col[e],     c1 = col[e + 1], c2 = col[e + 2], c3 = col[e + 3];
        float s0 = sbuf[e],    s1 = sbuf[e + 1];
        float s2 = sbuf[e + 2], s3 = sbuf[e + 3];
        u32 u0 = Xb2[(size_t)c0 * 64 + l];
        u32 u1 = Xb2[(size_t)c1 * 64 + l];
        u32 u2 = Xb2[(size_t)c2 * 64 + l];
        u32 u3 = Xb2[(size_t)c3 * 64 + l];
        ds += (s0 + s1) + (s2 + s3);
        p0 += s0 * __uint_as_float(u0 << 16);
        p1 += s0 * __uint_as_float(u0 & 0xffff0000u);
        q0 += s1 * __uint_as_float(u1 << 16);
        q1 += s1 * __uint_as_float(u1 & 0xffff0000u);
        p0 += s2 * __uint_as_float(u2 << 16);
        p1 += s2 * __uint_as_float(u2 & 0xffff0000u);
        q0 += s3 * __uint_as_float(u3 << 16);
        q1 += s3 * __uint_as_float(u3 & 0xffff0000u);
    }
    for (; e < e1; ++e) {
        int   c0 = col[e];
        float s0 = sbuf[e];
        u32 u0 = Xb2[(size_t)c0 * 64 + l];
        ds += s0;
        p0 += s0 * __uint_as_float(u0 << 16);
        p1 += s0 * __uint_as_float(u0 & 0xffff0000u);
    }
    p0 += q0; p1 += q1;
    float sc = 1.f / (ds + 1e-15f);
    aggb2[(size_t)n * 64 + l] = pack2(p0 * sc, p1 * sc);
}

// ---------------- fused (X@wres + agg@wx + biases) -> wo (+relu?) -----------
template<bool RELU>
__global__ __launch_bounds__(64) void gtm_fused(
    const u16* __restrict__ Xb, const u16* __restrict__ aggb,
    const u16* __restrict__ wres, const float* __restrict__ bres,
    const u16* __restrict__ wx, const float* __restrict__ bx,
    const u16* __restrict__ wo, const float* __restrict__ bo,
    u16* __restrict__ hb, int N)
{
    __shared__ u16 ylds[16 * D];                       // 4KB, wave-private
    const int l = threadIdx.x, l16 = l & 15, lg = l >> 4;
    const long r0 = (long)blockIdx.x * 16;
    const long ia = r0 + l16;
    bfrag xa[4], ga[4];
#pragma unroll
    for (int ks = 0; ks < 4; ++ks) {
        if (ia < N) {
            xa[ks] = *(const bfrag*)(Xb   + ia * D + ks * 32 + lg * 8);
            ga[ks] = *(const bfrag*)(aggb + ia * D + ks * 32 + lg * 8);
        } else { xa[ks] = bzero(); ga[ks] = bzero(); }
    }
    facc acc[8];
#pragma unroll
    for (int ct = 0; ct < 8; ++ct) acc[ct] = (facc){0, 0, 0, 0};
#pragma unroll
    for (int ks = 0; ks < 4; ++ks) {
#pragma unroll
        for (int ct = 0; ct < 8; ++ct) {
            bfrag b1 = *(const bfrag*)(wres + (((ct * 4 + ks) * 64 + l) << 3));
            acc[ct] = __builtin_amdgcn_mfma_f32_16x16x32_bf16(xa[ks], b1, acc[ct], 0, 0, 0);
            bfrag b2 = *(const bfrag*)(wx + (((ct * 4 + ks) * 64 + l) << 3));
            acc[ct] = __builtin_amdgcn_mfma_f32_16x16x32_bf16(ga[ks], b2, acc[ct], 0, 0, 0);
        }
    }
    // y = acc + (bres+bx) -> bf16 -> swizzled LDS
#pragma unroll
    for (int ct = 0; ct < 8; ++ct) {
        int col = ct * 16 + l16;
        float bsum = bres[col] + bx[col];
#pragma unroll
        for (int j = 0; j < 4; ++j) {
            int rl = lg * 4 + j;
            *(u16*)((char*)ylds + rl * 256
                    + ((((col >> 3) * 16) ^ ((rl & 7) << 4)) + (col & 7) * 2))
                = f2bf(acc[ct][j] + bsum);
        }
    }
    asm volatile("s_waitcnt lgkmcnt(0)" ::: "memory");
    __builtin_amdgcn_sched_barrier(0);
#pragma unroll
    for (int ct = 0; ct < 8; ++ct) acc[ct] = (facc){0, 0, 0, 0};
#pragma unroll
    for (int ks = 0; ks < 4; ++ks) {
        bfrag a = afrag16(ylds, l16, ks * 32 + lg * 8);
#pragma unroll
        for (int ct = 0; ct < 8; ++ct) {
            bfrag b = *(const bfrag*)(wo + (((ct * 4 + ks) * 64 + l) << 3));
            acc[ct] = __builtin_amdgcn_mfma_f32_16x16x32_bf16(a, b, acc[ct], 0, 0, 0);
        }
    }
#pragma unroll
    for (int ct = 0; ct < 8; ++ct) {
        int col = ct * 16 + l16;
        float bov = bo[col];
#pragma unroll
        for (int j = 0; j < 4; ++j) {
            long i = r0 + lg * 4 + j;
            if (i < N) {
                float y = acc[ct][j] + bov;
                if (RELU) y = fmaxf(y, 0.f);
                hb[i * D + col] = f2bf(y);
            }
        }
    }
}

// --------------------------------------------------------------- MLP tail ---
// 4 independent waves/block, each owns 16 rows + private LDS slice.
__device__ inline void ln_relu_to_lds(facc acc[12], const float* __restrict__ bb,
                                      const float* __restrict__ g,
                                      const float* __restrict__ bln,
                                      int l16, int lg, u16* wz)
{
    float s1[4] = {0, 0, 0, 0}, s2[4] = {0, 0, 0, 0};
#pragma unroll
    for (int ct = 0; ct < 12; ++ct) {
        float bbv = bb[ct * 16 + l16];
#pragma unroll
        for (int j = 0; j < 4; ++j) {
            float xv = acc[ct][j] + bbv;
            acc[ct][j] = xv;
            s1[j] += xv; s2[j] += xv * xv;
        }
    }
#pragma unroll
    for (int j = 0; j < 4; ++j) {
#pragma unroll
        for (int off = 1; off < 16; off <<= 1) {
            s1[j] += __shfl_xor(s1[j], off);
            s2[j] += __shfl_xor(s2[j], off);
        }
    }
#pragma unroll
    for (int ct = 0; ct < 12; ++ct) {
        int cc = ct * 16 + l16;
        float gv = g[cc], bv = bln[cc];
#pragma unroll
        for (int j = 0; j < 4; ++j) {
            float mu  = s1[j] * (1.f / 192.f);
            float var = s2[j] * (1.f / 192.f) - mu * mu;
            float y = (acc[ct][j] - mu) * rsqrtf(var + 1e-5f) * gv + bv;
            y = fmaxf(y, 0.f);
            int rl = lg * 4 + j;
            *(u16*)((char*)wz + rl * 384
                    + ((((cc >> 3) * 16) ^ ((rl & 7) << 4)) + (cc & 7) * 2)) = f2bf(y);
        }
    }
    asm volatile("s_waitcnt lgkmcnt(0)" ::: "memory");
    __builtin_amdgcn_sched_barrier(0);
}

__global__ __launch_bounds__(256) void mlp_tail3(
    const u16* __restrict__ hb,
    const int* __restrict__ src, const int* __restrict__ dst,
    const int* __restrict__ ebh, const u16* __restrict__ embb,
    const u16* __restrict__ w0, const float* __restrict__ b0,
    const u16* __restrict__ w1, const float* __restrict__ b1,
    const float* __restrict__ g, const float* __restrict__ bln,
    const u16* __restrict__ f0w, const float* __restrict__ f0b,
    const float* __restrict__ f1w, const float* __restrict__ f1b,
    float* __restrict__ out, int B)
{
    __shared__ u16 zs[4][16 * DMH];                    // per-wave 6KB slices
    const int t = threadIdx.x;
    const int w = t >> 6, l = t & 63, l16 = l & 15, lg = l >> 4;
    u16* wz = zs[w];
    const long r0 = (long)blockIdx.x * 64 + w * 16;
    const long ri = r0 + l16;

    // ---- z fragments built directly in registers
    bfrag za[6];
    if (ri < B) {
        int si = src[ri], di = dst[ri], hi2 = ebh[ri];
#pragma unroll
        for (int ks = 0; ks < 4; ++ks) {
            bfrag hs = *(const bfrag*)(hb + (size_t)si * D + ks * 32 + lg * 8);
            bfrag hd = *(const bfrag*)(hb + (size_t)di * D + ks * 32 + lg * 8);
            bfrag r;
#pragma unroll
            for (int k = 0; k < 8; ++k)
                r[k] = (short)f2bf(bf2f((u16)hs[k]) * bf2f((u16)hd[k]));
            za[ks] = r;
        }
        za[4] = *(const bfrag*)(embb + (size_t)hi2 * DE + lg * 8);
        za[5] = *(const bfrag*)(embb + (size_t)hi2 * DE + 32 + lg * 8);
    } else {
#pragma unroll
        for (int ks = 0; ks < 6; ++ks) za[ks] = bzero();
    }

    facc acc[12];
    // ---- layer 0: GEMM from registers (za dies here)
#pragma unroll
    for (int ct = 0; ct < 12; ++ct) acc[ct] = (facc){0, 0, 0, 0};
#pragma unroll
    for (int ks = 0; ks < 6; ++ks)
#pragma unroll
        for (int ct = 0; ct < 12; ++ct) {
            bfrag b = *(const bfrag*)(w0 + (((ct * 6 + ks) * 64 + l) << 3));
            acc[ct] = __builtin_amdgcn_mfma_f32_16x16x32_bf16(za[ks], b, acc[ct], 0, 0, 0);
        }
    ln_relu_to_lds(acc, b0, g, bln, l16, lg, wz);

    // ---- layer 1: GEMM from LDS
#pragma unroll
    for (int ct = 0; ct < 12; ++ct) acc[ct] = (facc){0, 0, 0, 0};
#pragma unroll
    for (int ks = 0; ks < 6; ++ks) {
        bfrag a = zfrag16(wz, l16, ks * 32 + lg * 8);
#pragma unroll
        for (int ct = 0; ct < 12; ++ct) {
            bfrag b = *(const bfrag*)(w1 + (((ct * 6 + ks) * 64 + l) << 3));
            acc[ct] = __builtin_amdgcn_mfma_f32_16x16x32_bf16(a, b, acc[ct], 0, 0, 0);
        }
    }
    ln_relu_to_lds(acc, b1, g, bln, l16, lg, wz);

    // ---- f0 (192->64), f1 (64->1), sigmoid
    facc o[4];
#pragma unroll
    for (int ct = 0; ct < 4; ++ct) o[ct] = (facc){0, 0, 0, 0};
#pragma unroll
    for (int ks = 0; ks < 6; ++ks) {
        bfrag a = zfrag16(wz, l16, ks * 32 + lg * 8);
#pragma unroll
        for (int ct = 0; ct < 4; ++ct) {
            bfrag b = *(const bfrag*)(f0w + (((ct * 6 + ks) * 64 + l) << 3));
            o[ct] = __builtin_amdgcn_mfma_f32_16x16x32_bf16(a, b, o[ct], 0, 0, 0);
        }
    }
    float p[4] = {0, 0, 0, 0};
#pragma unroll
    for (int ct = 0; ct < 4; ++ct) {
        int cc = ct * 16 + l16;
        float fb = f0b[cc], fw = f1w[cc];
#pragma unroll
        for (int j = 0; j < 4; ++j) p[j] += (o[ct][j] + fb) * fw;
    }
#pragma unroll
    for (int j = 0; j < 4; ++j) {
#pragma unroll
        for (int off = 1; off < 16; off <<= 1) p[j] += __shfl_xor(p[j], off);
    }
    if (l16 == 0) {
#pragma unroll
        for (int j = 0; j < 4; ++j) {
            long i = r0 + lg * 4 + j;
            if (i < B) out[i] = 1.f / (1.f + expf(-(p[j] + f1b[0])));
        }
    }
}

// ------------------------------------------------------------------ launch --
extern "C" void kernel_launch(void* const* d_in, const int* in_sizes, int n_in,
                              void* d_out, int out_size, void* d_ws, size_t ws_size,
                              hipStream_t stream)
{
    const float* x      = (const float*)d_in[0];
    const int*   row    = (const int*)d_in[1];
    const int*   col    = (const int*)d_in[2];
    const int*   eb_src = (const int*)d_in[3];
    const int*   eb_dst = (const int*)d_in[4];
    const int*   eb_h   = (const int*)d_in[5];
    const float* l_wres[2] = {(const float*)d_in[6],  (const float*)d_in[14]};
    const float* l_bres[2] = {(const float*)d_in[7],  (const float*)d_in[15]};
    const float* l_wr[2]   = {(const float*)d_in[8],  (const float*)d_in[16]};
    const float* l_wc[2]   = {(const float*)d_in[9],  (const float*)d_in[17]};
    const float* l_wx[2]   = {(const float*)d_in[10], (const float*)d_in[18]};
    const float* l_bx[2]   = {(const float*)d_in[11], (const float*)d_in[19]};
    const float* l_wo[2]   = {(const float*)d_in[12], (const float*)d_in[20]};
    const float* l_bo[2]   = {(const float*)d_in[13], (const float*)d_in[21]};
    const float* emb_h  = (const float*)d_in[22];
    const float* mlp0_w = (const float*)d_in[23];
    const float* mlp0_b = (const float*)d_in[24];
    const float* mlp1_w = (const float*)d_in[25];
    const float* mlp1_b = (const float*)d_in[26];
    const float* ln_g   = (const float*)d_in[27];
    const float* ln_b   = (const float*)d_in[28];
    const float* f0_w   = (const float*)d_in[29];
    const float* f0_b   = (const float*)d_in[30];
    const float* f1_w   = (const float*)d_in[31];
    const float* f1_b   = (const float*)d_in[32];

    const int N = in_sizes[0] / D;
    const int E = in_sizes[1];
    const int B = in_sizes[3];

    // workspace layout
    float* arb  = (float*)d_ws;                       // [N,8]
    float* acb  = arb + (size_t)N * DA;               // [N,8]
    float* sbuf = acb + (size_t)N * DA;               // [E]
    int* rowptr = (int*)(sbuf + (size_t)E);           // [N+1]
    uintptr_t bp = (uintptr_t)(rowptr + (N + 1));
    bp = (bp + 15) & ~(uintptr_t)15;
    u16* xb   = (u16*)bp;                             // [N,128] bf16
    u16* h0b  = xb  + (size_t)N * D;                  // [N,128] bf16
    u16* hfb  = h0b + (size_t)N * D;                  // [N,128] bf16
    u16* aggb = hfb + (size_t)N * D;                  // [N,128] bf16
    u16* WB   = aggb + (size_t)N * D;                 // 194880 bf16 weights

    const u16* WRES[2] = {WB + 0,     WB + 49152};
    const u16* WX[2]   = {WB + 16384, WB + 65536};
    const u16* WO[2]   = {WB + 32768, WB + 81920};
    const u16* MW0  = WB + 98304;
    const u16* MW1  = WB + 135168;
    const u16* F0W  = WB + 172032;
    const u16* WRC[2] = {WB + 184320, WB + 186368};
    const u16* EMBB = WB + 188416;

    PrepSrc ps;
    ps.p[0] = l_wres[0]; ps.p[1] = l_wx[0]; ps.p[2] = l_wo[0];
    ps.p[3] = l_wres[1]; ps.p[4] = l_wx[1]; ps.p[5] = l_wo[1];
    ps.p[6] = mlp0_w;    ps.p[7] = mlp1_w;  ps.p[8] = f0_w;
    ps.p[9] = l_wr[0];   ps.p[10] = l_wc[0];
    ps.p[11] = l_wr[1];  ps.p[12] = l_wc[1];
    ps.p[13] = emb_h;

    const int nb16  = (N + 15) / 16;
    const int nbE   = (E + 255) / 256;
    const int nbB64 = (B + 63) / 64;
    const long n8   = (long)N * D / 8;
    const long T    = 194880 + n8 + (long)E;
    const int nbT   = (int)((T + 255) / 256);

    prep_all<<<nbT, 256, 0, stream>>>(ps, WB, x, xb, n8, row, rowptr, E, N);

    const u16* lin[2] = {xb, h0b};
    u16* lout[2] = {h0b, hfb};
    for (int L = 0; L < 2; ++L) {
        calc_arac<<<nb16, 64, 0, stream>>>(lin[L], WRC[L], arb, acb, N);
        edge_score<<<nbE, 256, 0, stream>>>(row, col, arb, acb, sbuf, E);
        aggregate_b<<<N, 64, 0, stream>>>(rowptr, col, sbuf,
                                          (const u32*)lin[L], (u32*)aggb, N);
        if (L == 0)
            gtm_fused<true><<<nb16, 64, 0, stream>>>(
                lin[L], aggb, WRES[L], l_bres[L], WX[L], l_bx[L],
                WO[L], l_bo[L], lout[L], N);
        else
            gtm_fused<false><<<nb16, 64, 0, stream>>>(
                lin[L], aggb, WRES[L], l_bres[L], WX[L], l_bx[L],
                WO[L], l_bo[L], lout[L], N);
    }

    mlp_tail3<<<nbB64, 256, 0, stream>>>(
        hfb, eb_src, eb_dst, eb_h, EMBB,
        MW0, mlp0_b, MW1, mlp1_b, ln_g, ln_b,
        F0W, f0_b, f1_w, f1_b, (float*)d_out, B);
}